// Round 10
// baseline (718.675 us; speedup 1.0000x reference)
//
#include <hip/hip_runtime.h>

#define NV   163842
#define NF   327680
#define BB   2
#define INC  64
#define NECK 32
#define OUTC 128
#define NT   (BB*NV)
#define EPSB 1e-5f

typedef unsigned short ushort_t;
typedef __attribute__((ext_vector_type(8))) short bf16x8;
typedef __attribute__((ext_vector_type(4))) float f32x4;

// workspace float offsets
#define F_SX8  0
#define F_SS8  512
#define F_A1   33280
#define F_C1   33312
#define F_ASC  33344
#define F_CSC  33472
#define F_S2S  33600
#define F_S2Q  33632
#define F_A2   33664
#define F_C2   33696
#define F_SHR  33728
#define F_SS2  33760
#define F_A3   34784
#define F_C3   34912
#define F_CF   35040
#define STATN  35168
#define F_W1B  35200
#define F_CFB  36224
#define F_Y1   38272
#define F_H2   (F_Y1 + NT*16)
#define F_I18  (F_H2 + NT*16)
#define F_WEW  (F_I18 + NV*18)
#define F_WNS  (F_WEW + NV*18)
#define F_XB   (F_WNS + NV*18)

#define FSTR 136

__device__ __forceinline__ float bf2f(ushort_t u) {
    union { unsigned int i; float f; } x; x.i = ((unsigned int)u) << 16; return x.f;
}
__device__ __forceinline__ ushort_t f2bf(float f) {
    union { float f; unsigned int i; } x; x.f = f;
    unsigned int r = x.i + 0x7fffu + ((x.i >> 16) & 1u);
    return (ushort_t)(r >> 16);
}

// ---------------- prep: 18-pt stencil + coeffs->bf16 + w1->bf16 ----------------
__global__ __launch_bounds__(256) void k_prep(const int* __restrict__ idx_F2V,
                                              const float* __restrict__ vals_F2V,
                                              const int* __restrict__ idx_G,
                                              const float* __restrict__ vals_G,
                                              const float* __restrict__ EW,
                                              const float* __restrict__ NS,
                                              const float* __restrict__ coeffs,
                                              const float* __restrict__ w1,
                                              int* __restrict__ i18,
                                              float* __restrict__ wew,
                                              float* __restrict__ wns,
                                              ushort_t* __restrict__ cfb,
                                              ushort_t* __restrict__ w1b) {
    const int gid = blockIdx.x * 256 + threadIdx.x;
    if (gid < 4096) cfb[gid] = f2bf(coeffs[gid]);
    if (gid < 2048) w1b[gid] = f2bf(w1[gid]);
    const int n = gid;
    if (n >= NV) return;
#pragma unroll
    for (int k = 0; k < 6; ++k) {
        int f = idx_F2V[n * 6 + k];
        float fv = vals_F2V[n * 6 + k];
        float e0 = EW[f * 3], e1 = EW[f * 3 + 1], e2 = EW[f * 3 + 2];
        float s0 = NS[f * 3], s1 = NS[f * 3 + 1], s2 = NS[f * 3 + 2];
#pragma unroll
        for (int j = 0; j < 3; ++j) {
            float g0 = vals_G[f * 9 + j], g1 = vals_G[f * 9 + 3 + j], g2 = vals_G[f * 9 + 6 + j];
            i18[n * 18 + k * 3 + j] = idx_G[f * 3 + j];
            wew[n * 18 + k * 3 + j] = fv * (g0 * e0 + g1 * e1 + g2 * e2);
            wns[n * 18 + k * 3 + j] = fv * (g0 * s0 + g1 * s1 + g2 * s2);
        }
    }
}

// ---------------- xcvt v4: x -> xb + y1raw (fused conv1, no bn) + Sx/SS SYRK ----------------
__global__ __launch_bounds__(256, 3) void k_xcvt(const float* __restrict__ x,
                                                 const ushort_t* __restrict__ w1b,
                                                 float* __restrict__ ws,
                                                 ushort_t* __restrict__ xb,
                                                 ushort_t* __restrict__ y1) {
    __shared__ __align__(16) ushort_t TB[4][64 * 68];   // wave-private [vert][ch]
    __shared__ float SSl[64 * 68 + 64];
    const int tid = threadIdx.x;
    const int w = tid >> 6, l = tid & 63;
    const int o16 = l & 15, kg = l >> 4;
    ushort_t* TBw = &TB[w][0];

    for (int i = tid; i < 64 * 68 + 64; i += 256) SSl[i] = 0.f;
    __syncthreads();

    // conv1 A-frags (w1 raw bf16)
    bf16x8 aw[2][2];
#pragma unroll
    for (int mt = 0; mt < 2; ++mt)
#pragma unroll
        for (int ks = 0; ks < 2; ++ks)
            aw[mt][ks] = *(const bf16x8*)(w1b + (mt * 16 + o16) * 64 + ks * 32 + kg * 8);

    f32x4 acc[10];
#pragma unroll
    for (int i = 0; i < 10; ++i) acc[i] = (f32x4){0.f, 0.f, 0.f, 0.f};
    f32x4 accS[4];
#pragma unroll
    for (int i = 0; i < 4; ++i) accS[i] = (f32x4){0.f, 0.f, 0.f, 0.f};

    bf16x8 onesf;
    {
        short ov = (o16 == 0) ? (short)0x3F80 : (short)0;
#pragma unroll
        for (int j = 0; j < 8; ++j) onesf[j] = ov;
    }

    const int NCHB = (NV + 63) >> 6;   // 2561 per batch
    const int NW = gridDim.x * 4;
    for (int cid = blockIdx.x * 4 + w; cid < 2 * NCHB; cid += NW) {
        const int b = (cid >= NCHB) ? 1 : 0;
        const int tc = cid - b * NCHB;
        const int n0 = tc << 6;
        const float* xsrc = x + (size_t)b * 64 * NV;
        const bool full = (n0 + 64 <= NV);
        // ---- (a) vertex-per-lane: load 64ch, write xb + LDS tile
        {
            const int n = n0 + l;
            ushort_t* trow = TBw + l * 68;
            if (n < NV) {
                unsigned int pk[32];
#pragma unroll
                for (int c2 = 0; c2 < 32; ++c2) {
                    float f0 = xsrc[(size_t)(2 * c2) * NV + n];
                    float f1 = xsrc[(size_t)(2 * c2 + 1) * NV + n];
                    pk[c2] = (unsigned int)f2bf(f0) | ((unsigned int)f2bf(f1) << 16);
                }
                ushort_t* row = xb + (size_t)(b * NV + n) * 64;
#pragma unroll
                for (int j = 0; j < 8; ++j) {
                    uint4 q = make_uint4(pk[4 * j], pk[4 * j + 1], pk[4 * j + 2], pk[4 * j + 3]);
                    *(uint4*)(row + j * 8) = q;
                    *(uint4*)(trow + j * 8) = q;
                }
            } else {
                uint4 z = make_uint4(0u, 0u, 0u, 0u);
#pragma unroll
                for (int j = 0; j < 8; ++j) *(uint4*)(trow + j * 8) = z;
            }
        }
        // ---- conv1: y1raw = w1 . x  (B-frags from wave-private LDS)
        {
            bf16x8 bfc[4][2];
#pragma unroll
            for (int nt = 0; nt < 4; ++nt)
#pragma unroll
                for (int ks = 0; ks < 2; ++ks)
                    bfc[nt][ks] = *(const bf16x8*)(TBw + (nt * 16 + o16) * 68 + ks * 32 + kg * 8);
            f32x4 ac1[2][4];
#pragma unroll
            for (int mt = 0; mt < 2; ++mt)
#pragma unroll
                for (int nt = 0; nt < 4; ++nt) ac1[mt][nt] = (f32x4){0.f, 0.f, 0.f, 0.f};
#pragma unroll
            for (int mt = 0; mt < 2; ++mt)
#pragma unroll
                for (int nt = 0; nt < 4; ++nt)
#pragma unroll
                    for (int ks = 0; ks < 2; ++ks)
                        ac1[mt][nt] = __builtin_amdgcn_mfma_f32_16x16x32_bf16(aw[mt][ks], bfc[nt][ks], ac1[mt][nt], 0, 0, 0);
#pragma unroll
            for (int nt = 0; nt < 4; ++nt) {
                const int vert = n0 + nt * 16 + o16;
                if (vert < NV) {
#pragma unroll
                    for (int mt = 0; mt < 2; ++mt) {
                        uint2 p;
                        p.x = (unsigned)f2bf(ac1[mt][nt][0]) | ((unsigned)f2bf(ac1[mt][nt][1]) << 16);
                        p.y = (unsigned)f2bf(ac1[mt][nt][2]) | ((unsigned)f2bf(ac1[mt][nt][3]) << 16);
                        *(uint2*)(y1 + ((size_t)b * NV + vert) * 32 + mt * 16 + kg * 4) = p;
                    }
                }
            }
        }
        // ---- (b) ch-major frags from global (L1-hot), SYRK
        bf16x8 fr[4][2];
#pragma unroll
        for (int mt = 0; mt < 4; ++mt) {
            const float* rp = xsrc + (size_t)(mt * 16 + o16) * NV + n0;
#pragma unroll
            for (int ks = 0; ks < 2; ++ks) {
                const int v0 = ks * 32 + kg * 8;
                float f[8];
                if (full) {
                    float4 q0 = *(const float4*)(rp + v0);
                    float4 q1 = *(const float4*)(rp + v0 + 4);
                    f[0] = q0.x; f[1] = q0.y; f[2] = q0.z; f[3] = q0.w;
                    f[4] = q1.x; f[5] = q1.y; f[6] = q1.z; f[7] = q1.w;
                } else {
#pragma unroll
                    for (int j = 0; j < 8; ++j)
                        f[j] = (n0 + v0 + j < NV) ? rp[v0 + j] : 0.f;
                }
                bf16x8 fb;
#pragma unroll
                for (int j = 0; j < 8; ++j) fb[j] = (short)f2bf(f[j]);
                fr[mt][ks] = fb;
            }
        }
#pragma unroll
        for (int ks = 0; ks < 2; ++ks) {
            int tt = 0;
#pragma unroll
            for (int mt = 0; mt < 4; ++mt) {
#pragma unroll
                for (int nt2 = 0; nt2 < 4; ++nt2) {
                    if (nt2 >= mt) {
                        acc[tt] = __builtin_amdgcn_mfma_f32_16x16x32_bf16(fr[mt][ks], fr[nt2][ks], acc[tt], 0, 0, 0);
                        ++tt;
                    }
                }
                accS[mt] = __builtin_amdgcn_mfma_f32_16x16x32_bf16(onesf, fr[mt][ks], accS[mt], 0, 0, 0);
            }
        }
    }
    // ---- dump
    {
        int tt = 0;
#pragma unroll
        for (int mt = 0; mt < 4; ++mt) {
#pragma unroll
            for (int nt2 = 0; nt2 < 4; ++nt2) {
                if (nt2 >= mt) {
#pragma unroll
                    for (int r = 0; r < 4; ++r)
                        atomicAdd(&SSl[(mt * 16 + kg * 4 + r) * 68 + nt2 * 16 + o16], acc[tt][r]);
                    ++tt;
                }
            }
            if (kg == 0) atomicAdd(&SSl[64 * 68 + mt * 16 + o16], accS[mt][0]);
        }
    }
    __syncthreads();
    {
        float* SSg = ws + F_SS8 + (size_t)(blockIdx.x & 7) * 4096;
        for (int i = tid; i < 64 * 64; i += 256) {
            const int r = i >> 6, c = i & 63;
            if (c >= r) {
                float v = SSl[r * 68 + c];
                if (v != 0.f) atomicAdd(&SSg[r * 64 + c], v);
            }
        }
        if (tid < 64) atomicAdd(&ws[F_SX8 + (blockIdx.x & 7) * 64 + tid], SSl[64 * 68 + tid]);
    }
}

// ---------------- fold1: BN1 + BNsc params from x moments ----------------
__global__ __launch_bounds__(256) void k_fold1(const float* __restrict__ w1,
                                               const float* __restrict__ g1,
                                               const float* __restrict__ be1,
                                               const float* __restrict__ wsc,
                                               const float* __restrict__ gsc,
                                               const float* __restrict__ besc,
                                               float* __restrict__ ws) {
    __shared__ float SSl[4096];
    __shared__ float Sxl[64];
    const int tid = threadIdx.x;
    for (int i = tid; i < 4096; i += 256) {
        const int r = i >> 6, c = i & 63;
        float v = 0.f;
        if (c >= r) {
#pragma unroll
            for (int s = 0; s < 8; ++s) v += ws[F_SS8 + s * 4096 + i];
        }
        SSl[i] = v;
    }
    if (tid < 64) {
        float v = 0.f;
#pragma unroll
        for (int s = 0; s < 8; ++s) v += ws[F_SX8 + s * 64 + tid];
        Sxl[tid] = v;
    }
    __syncthreads();
    for (int i = tid; i < 4096; i += 256) {
        const int r = i >> 6, c = i & 63;
        if (c < r) SSl[i] = SSl[c * 64 + r];
    }
    __syncthreads();
    if (tid >= 32) return;
    const int bk = blockIdx.x;
    const float* w;
    float gamma, beta;
    float *pa, *pc;
    if (bk == 0) {
        w = w1 + tid * 64; gamma = g1[tid]; beta = be1[tid];
        pa = ws + F_A1 + tid; pc = ws + F_C1 + tid;
    } else {
        int o = (bk - 1) * 32 + tid;
        w = wsc + o * 64; gamma = gsc[o]; beta = besc[o];
        pa = ws + F_ASC + o; pc = ws + F_CSC + o;
    }
    float4 wr[16];
#pragma unroll
    for (int i = 0; i < 16; ++i) wr[i] = *(const float4*)(w + i * 4);
    float dotm = 0.f, quad = 0.f;
#pragma unroll
    for (int i4 = 0; i4 < 16; ++i4) {
        float4 wi = wr[i4];
        float rd[4] = {0.f, 0.f, 0.f, 0.f};
#pragma unroll
        for (int j4 = 0; j4 < 16; ++j4) {
            float4 wj = wr[j4];
#pragma unroll
            for (int r = 0; r < 4; ++r) {
                const float* row = &SSl[(i4 * 4 + r) * 64 + j4 * 4];
                rd[r] += row[0] * wj.x + row[1] * wj.y + row[2] * wj.z + row[3] * wj.w;
            }
        }
        dotm += wi.x * Sxl[i4 * 4] + wi.y * Sxl[i4 * 4 + 1] + wi.z * Sxl[i4 * 4 + 2] + wi.w * Sxl[i4 * 4 + 3];
        quad += wi.x * rd[0] + wi.y * rd[1] + wi.z * rd[2] + wi.w * rd[3];
    }
    const float invN = 1.0f / (float)NT;
    const float mean0 = dotm * invN;
    const float var = quad * invN - mean0 * mean0;
    const float a = gamma * rsqrtf(var + EPSB);
    *pa = a;
    *pc = beta - a * mean0;
}

// ---------------- meshconv v4: combined-batch chunks, per-lane metadata, bn1 fused ----------------
// lanes: gh = lane>>5 (vertex-in-pair), bh = (lane>>4)&1 (batch), c2 = lane&15 (ch pair)
__global__ __launch_bounds__(256, 4) void k_meshconv(const ushort_t* __restrict__ y1,
                                                     const ushort_t* __restrict__ cfb,
                                                     const int* __restrict__ idx_L,
                                                     const float* __restrict__ vals_L,
                                                     const int* __restrict__ i18,
                                                     const float* __restrict__ w18ew,
                                                     const float* __restrict__ w18ns,
                                                     ushort_t* __restrict__ h2,
                                                     float* __restrict__ ws) {
    __shared__ __align__(16) ushort_t feat[4][32 * FSTR];
    __shared__ float sred[64];
    const int tid = threadIdx.x;
    const int w = __builtin_amdgcn_readfirstlane(tid >> 6);
    const int lane = tid & 63;
    ushort_t* fw = &feat[w][0];
    const int gh = lane >> 5;
    const int bh = (lane >> 4) & 1;
    const int c2 = lane & 15;
    const int o16 = lane & 15;
    const int kg = lane >> 4;

    const float a1_0 = ws[F_A1 + 2 * c2], a1_1 = ws[F_A1 + 2 * c2 + 1];
    const float c1_0 = ws[F_C1 + 2 * c2], c1_1 = ws[F_C1 + 2 * c2 + 1];

    if (tid < 64) sred[tid] = 0.f;
    __syncthreads();

    float ssum[8], sssq[8];
#pragma unroll
    for (int i = 0; i < 8; ++i) { ssum[i] = 0.f; sssq[i] = 0.f; }

    const int gw = blockIdx.x * 4 + w;
    const int NW = gridDim.x * 4;
    const int NCH = (NV + 15) >> 4;  // 10241

    for (int ch = gw; ch < NCH; ch += NW) {
        const int n0 = ch << 4;
        const ushort_t* yb = y1 + (size_t)bh * (NV * 32);
        for (int jj = 0; jj < 8; ++jj) {
            const int n = n0 + jj * 2 + gh;
            const bool ok = (n < NV);
            const int nn = ok ? n : NV - 1;
            // self (bn1+relu)
            unsigned int qs = *(const unsigned int*)(yb + (nn << 5) + (c2 << 1));
            float fx0 = fmaxf(fmaf(a1_0, bf2f((ushort_t)(qs & 0xffffu)), c1_0), 0.f);
            float fx1 = fmaxf(fmaf(a1_1, bf2f((ushort_t)(qs >> 16)), c1_1), 0.f);
            float lap0 = 0.f, lap1 = 0.f, ge0 = 0.f, ge1 = 0.f, gn0 = 0.f, gn1 = 0.f;
            const int* ilp = idx_L + nn * 7;
            const float* vlp = vals_L + nn * 7;
#pragma unroll
            for (int j = 0; j < 7; ++j) {
                const int vi = ilp[j];
                const float wv = vlp[j];
                unsigned int q = *(const unsigned int*)(yb + (vi << 5) + (c2 << 1));
                float v0 = fmaxf(fmaf(a1_0, bf2f((ushort_t)(q & 0xffffu)), c1_0), 0.f);
                float v1 = fmaxf(fmaf(a1_1, bf2f((ushort_t)(q >> 16)), c1_1), 0.f);
                lap0 += wv * v0;
                lap1 += wv * v1;
            }
            const int* igp = i18 + nn * 18;
            const float* wep = w18ew + nn * 18;
            const float* wnp = w18ns + nn * 18;
#pragma unroll
            for (int j = 0; j < 18; ++j) {
                const int vi = igp[j];
                const float we = wep[j], wn = wnp[j];
                unsigned int q = *(const unsigned int*)(yb + (vi << 5) + (c2 << 1));
                float v0 = fmaxf(fmaf(a1_0, bf2f((ushort_t)(q & 0xffffu)), c1_0), 0.f);
                float v1 = fmaxf(fmaf(a1_1, bf2f((ushort_t)(q >> 16)), c1_1), 0.f);
                ge0 += we * v0; ge1 += we * v1;
                gn0 += wn * v0; gn1 += wn * v1;
            }
            unsigned int u0 = 0u, u1 = 0u, u2 = 0u, u3 = 0u;
            if (ok) {
                u0 = (unsigned int)f2bf(fx0) | ((unsigned int)f2bf(lap0) << 16);
                u1 = (unsigned int)f2bf(ge0) | ((unsigned int)f2bf(gn0) << 16);
                u2 = (unsigned int)f2bf(fx1) | ((unsigned int)f2bf(lap1) << 16);
                u3 = (unsigned int)f2bf(ge1) | ((unsigned int)f2bf(gn1) << 16);
            }
            const int inst = bh * 16 + jj * 2 + gh;
            *(uint4*)(fw + inst * FSTR + (c2 << 3)) = make_uint4(u0, u1, u2, u3);
        }
        // ---- MFMA: D[o=32][inst=32] = coeffs[32x128] * feat[128x32]
        f32x4 acc[2][2];
#pragma unroll
        for (int mt = 0; mt < 2; ++mt)
#pragma unroll
            for (int nt = 0; nt < 2; ++nt) acc[mt][nt] = (f32x4){0.f, 0.f, 0.f, 0.f};
        bf16x8 bfr[2][4];
#pragma unroll
        for (int nt = 0; nt < 2; ++nt)
#pragma unroll
            for (int kt = 0; kt < 4; ++kt)
                bfr[nt][kt] = *(const bf16x8*)(fw + (nt * 16 + o16) * FSTR + kt * 32 + kg * 8);
#pragma unroll
        for (int mt = 0; mt < 2; ++mt) {
#pragma unroll
            for (int kt = 0; kt < 4; ++kt) {
                bf16x8 af = *(const bf16x8*)(cfb + (mt * 16 + o16) * 128 + kt * 32 + kg * 8);
                acc[mt][0] = __builtin_amdgcn_mfma_f32_16x16x32_bf16(af, bfr[0][kt], acc[mt][0], 0, 0, 0);
                acc[mt][1] = __builtin_amdgcn_mfma_f32_16x16x32_bf16(af, bfr[1][kt], acc[mt][1], 0, 0, 0);
            }
        }
        const int n = n0 + o16;
        if (n < NV) {
#pragma unroll
            for (int nt = 0; nt < 2; ++nt) {
                const int rowb = ((nt * NV + n) << 5);
#pragma unroll
                for (int mt = 0; mt < 2; ++mt) {
#pragma unroll
                    for (int r = 0; r < 4; ++r) {
                        float v = acc[mt][nt][r];
                        int o = mt * 16 + kg * 4 + r;
                        h2[rowb + o] = f2bf(v);
                        ssum[mt * 4 + r] += v;
                        sssq[mt * 4 + r] += v * v;
                    }
                }
            }
        }
    }

#pragma unroll
    for (int si = 0; si < 8; ++si) {
#pragma unroll
        for (int m = 1; m < 16; m <<= 1) {
            ssum[si] += __shfl_xor(ssum[si], m, 16);
            sssq[si] += __shfl_xor(sssq[si], m, 16);
        }
    }
    if (o16 == 0) {
#pragma unroll
        for (int mt = 0; mt < 2; ++mt)
#pragma unroll
            for (int r = 0; r < 4; ++r) {
                int o = mt * 16 + kg * 4 + r;
                atomicAdd(&sred[o], ssum[mt * 4 + r]);
                atomicAdd(&sred[32 + o], sssq[mt * 4 + r]);
            }
    }
    __syncthreads();
    if (tid < 64) atomicAdd(&ws[F_S2S + tid], sred[tid]);
}

// ---------------- hr moments (fold2 fused as prologue) ----------------
__global__ __launch_bounds__(256) void k_hrmoments(const ushort_t* __restrict__ h2,
                                                   const float* __restrict__ g2,
                                                   const float* __restrict__ be2,
                                                   float* __restrict__ ws) {
    __shared__ __align__(16) ushort_t tile[4][32 * 40];
    __shared__ float red[1056];
    __shared__ float sA2[32], sC2[32];
    const int tid = threadIdx.x;
    const int w = tid >> 6, l = tid & 63;
    ushort_t* T = &tile[w][0];
    const int c8 = (l & 3) * 8;
    const int v0 = l >> 2;
    const int fr = l & 15, kg = l >> 4;

    if (tid < 32) {
        const float invN = 1.0f / (float)NT;
        float m = ws[F_S2S + tid] * invN;
        float var = ws[F_S2Q + tid] * invN - m * m;
        float a = g2[tid] * rsqrtf(var + EPSB);
        float c = be2[tid] - a * m;
        sA2[tid] = a; sC2[tid] = c;
        ws[F_A2 + tid] = a; ws[F_C2 + tid] = c;   // all blocks write identical values
    }
    for (int i = tid; i < 1056; i += 256) red[i] = 0.f;
    __syncthreads();

    float a2r[8], c2r[8];
#pragma unroll
    for (int j = 0; j < 8; ++j) { a2r[j] = sA2[c8 + j]; c2r[j] = sC2[c8 + j]; }

    f32x4 acc[2][2];
#pragma unroll
    for (int a = 0; a < 2; ++a)
#pragma unroll
        for (int b = 0; b < 2; ++b) acc[a][b] = (f32x4){0.f, 0.f, 0.f, 0.f};
    float ssum[8];
#pragma unroll
    for (int j = 0; j < 8; ++j) ssum[j] = 0.f;

    const int NCH = (NT + 31) >> 5;
    for (int ch = blockIdx.x * 4 + w; ch < NCH; ch += gridDim.x * 4) {
        const int s0 = ch << 5;
#pragma unroll
        for (int i = 0; i < 2; ++i) {
            const int vert = i * 16 + v0;
            const int s = s0 + vert;
            uint4 q = make_uint4(0u, 0u, 0u, 0u);
            const bool ok = (s < NT);
            if (ok) q = *(const uint4*)(h2 + (size_t)s * 32 + c8);
            const ushort_t* qs = (const ushort_t*)&q;
            ushort_t hb[8];
#pragma unroll
            for (int j = 0; j < 8; ++j) {
                float hv = ok ? fmaxf(a2r[j] * bf2f(qs[j]) + c2r[j], 0.f) : 0.f;
                ssum[j] += hv;
                hb[j] = f2bf(hv);
            }
#pragma unroll
            for (int j = 0; j < 8; ++j) T[(c8 + j) * 40 + vert] = hb[j];
        }
        bf16x8 f0 = *(const bf16x8*)(T + fr * 40 + kg * 8);
        bf16x8 f1 = *(const bf16x8*)(T + (16 + fr) * 40 + kg * 8);
        acc[0][0] = __builtin_amdgcn_mfma_f32_16x16x32_bf16(f0, f0, acc[0][0], 0, 0, 0);
        acc[0][1] = __builtin_amdgcn_mfma_f32_16x16x32_bf16(f0, f1, acc[0][1], 0, 0, 0);
        acc[1][0] = __builtin_amdgcn_mfma_f32_16x16x32_bf16(f1, f0, acc[1][0], 0, 0, 0);
        acc[1][1] = __builtin_amdgcn_mfma_f32_16x16x32_bf16(f1, f1, acc[1][1], 0, 0, 0);
    }
#pragma unroll
    for (int mt = 0; mt < 2; ++mt)
#pragma unroll
        for (int nt = 0; nt < 2; ++nt)
#pragma unroll
            for (int r = 0; r < 4; ++r)
                atomicAdd(&red[(mt * 16 + kg * 4 + r) * 32 + nt * 16 + fr], acc[mt][nt][r]);
#pragma unroll
    for (int j = 0; j < 8; ++j) {
        float s = ssum[j];
        s += __shfl_xor(s, 4); s += __shfl_xor(s, 8);
        s += __shfl_xor(s, 16); s += __shfl_xor(s, 32);
        if (v0 == 0) atomicAdd(&red[1024 + c8 + j], s);
    }
    __syncthreads();
    for (int i = tid; i < 1024; i += 256) atomicAdd(&ws[F_SS2 + i], red[i]);
    if (tid < 32) atomicAdd(&ws[F_SHR + tid], red[1024 + tid]);
}

// ---------------- fold3: BN3 params + fused final weights Wf (bf16) ----------------
__global__ __launch_bounds__(128) void k_fold3(const float* __restrict__ w3,
                                               const float* __restrict__ wsc,
                                               const float* __restrict__ g3,
                                               const float* __restrict__ be3,
                                               float* __restrict__ ws,
                                               ushort_t* __restrict__ wfb) {
    __shared__ float SSl[1024];
    __shared__ float Sl[32];
    const int tid = threadIdx.x;
    for (int i = tid; i < 1024; i += 128) SSl[i] = ws[F_SS2 + i];
    if (tid < 32) Sl[tid] = ws[F_SHR + tid];
    __syncthreads();
    const int o = tid;
    float4 wr[8];
#pragma unroll
    for (int i = 0; i < 8; ++i) wr[i] = *(const float4*)(w3 + o * 32 + i * 4);
    float dotm = 0.f, quad = 0.f;
#pragma unroll
    for (int i4 = 0; i4 < 8; ++i4) {
        float4 wi = wr[i4];
        float rd[4] = {0.f, 0.f, 0.f, 0.f};
#pragma unroll
        for (int j4 = 0; j4 < 8; ++j4) {
            float4 wj = wr[j4];
#pragma unroll
            for (int r = 0; r < 4; ++r) {
                const float* row = &SSl[(i4 * 4 + r) * 32 + j4 * 4];
                rd[r] += row[0] * wj.x + row[1] * wj.y + row[2] * wj.z + row[3] * wj.w;
            }
        }
        dotm += wi.x * Sl[i4 * 4] + wi.y * Sl[i4 * 4 + 1] + wi.z * Sl[i4 * 4 + 2] + wi.w * Sl[i4 * 4 + 3];
        quad += wi.x * rd[0] + wi.y * rd[1] + wi.z * rd[2] + wi.w * rd[3];
    }
    const float invN = 1.0f / (float)NT;
    const float mean0 = dotm * invN;
    const float var = quad * invN - mean0 * mean0;
    const float a = g3[o] * rsqrtf(var + EPSB);
    const float cbias = be3[o] - a * mean0;
    ws[F_A3 + o] = a;
    ws[F_C3 + o] = cbias;
    const float asc = ws[F_ASC + o], csc = ws[F_CSC + o];
    ws[F_CF + o] = cbias + csc;
#pragma unroll
    for (int i4 = 0; i4 < 8; ++i4) {
        wfb[o * 96 + i4 * 4 + 0] = f2bf(a * wr[i4].x);
        wfb[o * 96 + i4 * 4 + 1] = f2bf(a * wr[i4].y);
        wfb[o * 96 + i4 * 4 + 2] = f2bf(a * wr[i4].z);
        wfb[o * 96 + i4 * 4 + 3] = f2bf(a * wr[i4].w);
    }
    for (int j = 0; j < 64; ++j)
        wfb[o * 96 + 32 + j] = f2bf(asc * wsc[o * 64 + j]);
}

// ---------------- final: fused [conv3+bn3 | conv_sc+bn_sc] MFMA GEMM + relu ----------------
__global__ __launch_bounds__(256) void k_final(const ushort_t* __restrict__ xb,
                                               const ushort_t* __restrict__ h2,
                                               const ushort_t* __restrict__ wfb,
                                               const float* __restrict__ ws,
                                               float* __restrict__ out) {
    __shared__ __align__(16) ushort_t feat[32 * 104];
    const int tid = threadIdx.x;
    const int w = tid >> 6, l = tid & 63;
    const int fr = l & 15, kg = l >> 4;

    bf16x8 af[2][3];
#pragma unroll
    for (int mt = 0; mt < 2; ++mt)
#pragma unroll
        for (int kt = 0; kt < 3; ++kt)
            af[mt][kt] = *(const bf16x8*)(wfb + (w * 32 + mt * 16 + fr) * 96 + kt * 32 + kg * 8);
    float cfr[2][4];
#pragma unroll
    for (int mt = 0; mt < 2; ++mt)
#pragma unroll
        for (int r = 0; r < 4; ++r)
            cfr[mt][r] = ws[F_CF + w * 32 + mt * 16 + kg * 4 + r];

    const int hv = tid >> 3, hc4 = (tid & 7) * 4;
    float a2r[4], c2r[4];
#pragma unroll
    for (int j = 0; j < 4; ++j) { a2r[j] = ws[F_A2 + hc4 + j]; c2r[j] = ws[F_C2 + hc4 + j]; }
    const int xv = tid >> 3, xseg = tid & 7;

    const int NCHK = (NV + 31) >> 5;  // 5121
    for (int cid = blockIdx.x; cid < 2 * NCHK; cid += gridDim.x) {
        const int b = (cid >= NCHK) ? 1 : 0;
        const int t = cid - b * NCHK;
        const int n0 = t << 5;
        const int rem = NV - n0 < 32 ? NV - n0 : 32;
        {
            const int s = b * NV + n0 + hv;
            const bool ok = (hv < rem);
            uint2 q = make_uint2(0u, 0u);
            if (ok) q = *(const uint2*)(h2 + (size_t)s * 32 + hc4);
            const ushort_t* qs = (const ushort_t*)&q;
            unsigned int p0 = 0u, p1 = 0u;
            if (ok) {
                float h0 = fmaxf(a2r[0] * bf2f(qs[0]) + c2r[0], 0.f);
                float h1 = fmaxf(a2r[1] * bf2f(qs[1]) + c2r[1], 0.f);
                float h2v = fmaxf(a2r[2] * bf2f(qs[2]) + c2r[2], 0.f);
                float h3 = fmaxf(a2r[3] * bf2f(qs[3]) + c2r[3], 0.f);
                p0 = (unsigned int)f2bf(h0) | ((unsigned int)f2bf(h1) << 16);
                p1 = (unsigned int)f2bf(h2v) | ((unsigned int)f2bf(h3) << 16);
            }
            *(uint2*)(feat + hv * 104 + hc4) = make_uint2(p0, p1);
        }
        {
            const int s = b * NV + n0 + xv;
            uint4 q = make_uint4(0u, 0u, 0u, 0u);
            if (xv < rem) q = *(const uint4*)(xb + (size_t)s * 64 + xseg * 8);
            *(uint4*)(feat + xv * 104 + 32 + xseg * 8) = q;
        }
        __syncthreads();
        bf16x8 bf[2][3];
#pragma unroll
        for (int nt = 0; nt < 2; ++nt)
#pragma unroll
            for (int kt = 0; kt < 3; ++kt)
                bf[nt][kt] = *(const bf16x8*)(feat + (nt * 16 + fr) * 104 + kt * 32 + kg * 8);
        __syncthreads();
        f32x4 acc[2][2];
#pragma unroll
        for (int mt = 0; mt < 2; ++mt)
#pragma unroll
            for (int nt = 0; nt < 2; ++nt) acc[mt][nt] = (f32x4){0.f, 0.f, 0.f, 0.f};
#pragma unroll
        for (int mt = 0; mt < 2; ++mt)
#pragma unroll
            for (int nt = 0; nt < 2; ++nt)
#pragma unroll
                for (int kt = 0; kt < 3; ++kt)
                    acc[mt][nt] = __builtin_amdgcn_mfma_f32_16x16x32_bf16(af[mt][kt], bf[nt][kt], acc[mt][nt], 0, 0, 0);
#pragma unroll
        for (int mt = 0; mt < 2; ++mt) {
#pragma unroll
            for (int nt = 0; nt < 2; ++nt) {
                const int col = n0 + nt * 16 + fr;
                if (col < NV) {
                    float* po = out + (size_t)(b * 128 + w * 32 + mt * 16 + kg * 4) * NV + col;
#pragma unroll
                    for (int r = 0; r < 4; ++r)
                        po[(size_t)r * NV] = fmaxf(acc[mt][nt][r] + cfr[mt][r], 0.f);
                }
            }
        }
    }
}

extern "C" void kernel_launch(void* const* d_in, const int* in_sizes, int n_in,
                              void* d_out, int out_size, void* d_ws, size_t ws_size,
                              hipStream_t stream) {
    (void)in_sizes; (void)n_in; (void)out_size; (void)ws_size;
    const float* x        = (const float*)d_in[0];
    const float* w1       = (const float*)d_in[1];
    const float* g1       = (const float*)d_in[3];
    const float* be1      = (const float*)d_in[4];
    const float* coeffs   = (const float*)d_in[5];
    const float* g2       = (const float*)d_in[7];
    const float* be2      = (const float*)d_in[8];
    const float* w3       = (const float*)d_in[9];
    const float* g3       = (const float*)d_in[11];
    const float* be3      = (const float*)d_in[12];
    const float* wsc      = (const float*)d_in[13];
    const float* gsc      = (const float*)d_in[15];
    const float* besc     = (const float*)d_in[16];
    const int*   idx_G    = (const int*)d_in[17];
    const float* vals_G   = (const float*)d_in[18];
    const float* EW       = (const float*)d_in[19];
    const float* NS       = (const float*)d_in[20];
    const int*   idx_L    = (const int*)d_in[21];
    const float* vals_L   = (const float*)d_in[22];
    const int*   idx_F2V  = (const int*)d_in[23];
    const float* vals_F2V = (const float*)d_in[24];
    float* ws  = (float*)d_ws;
    float* out = (float*)d_out;

    ushort_t* w1b = (ushort_t*)(ws + F_W1B);
    ushort_t* cfb = (ushort_t*)(ws + F_CFB);
    ushort_t* y1  = (ushort_t*)(ws + F_Y1);
    ushort_t* h2  = (ushort_t*)(ws + F_H2);
    ushort_t* xb  = (ushort_t*)(ws + F_XB);
    ushort_t* wfb = (ushort_t*)(ws + F_Y1);  // aliases y1 (dead after meshconv)

    hipMemsetAsync(ws, 0, STATN * sizeof(float), stream);
    hipLaunchKernelGGL(k_prep, dim3((NV + 255) / 256), dim3(256), 0, stream,
                       idx_F2V, vals_F2V, idx_G, vals_G, EW, NS, coeffs, w1,
                       (int*)(ws + F_I18), ws + F_WEW, ws + F_WNS, cfb, w1b);
    hipLaunchKernelGGL(k_xcvt, dim3(1280), dim3(256), 0, stream, x, w1b, ws, xb, y1);
    hipLaunchKernelGGL(k_fold1, dim3(5), dim3(256), 0, stream, w1, g1, be1, wsc, gsc, besc, ws);
    hipLaunchKernelGGL(k_meshconv, dim3(1024), dim3(256), 0, stream,
                       y1, cfb, idx_L, vals_L,
                       (const int*)(ws + F_I18), ws + F_WEW, ws + F_WNS,
                       h2, ws);
    hipLaunchKernelGGL(k_hrmoments, dim3(1024), dim3(256), 0, stream, h2, g2, be2, ws);
    hipLaunchKernelGGL(k_fold3, dim3(1), dim3(128), 0, stream, w3, wsc, g3, be3, ws, wfb);
    hipLaunchKernelGGL(k_final, dim3(2048), dim3(256), 0, stream, xb, h2, wfb, ws, out);
}

// Round 11
// 538.306 us; speedup vs baseline: 1.3351x; 1.3351x over previous
//
#include <hip/hip_runtime.h>

#define NV   163842
#define NF   327680
#define BB   2
#define INC  64
#define NECK 32
#define OUTC 128
#define NT   (BB*NV)
#define EPSB 1e-5f

typedef unsigned short ushort_t;
typedef __attribute__((ext_vector_type(8))) short bf16x8;
typedef __attribute__((ext_vector_type(4))) float f32x4;

// workspace float offsets
#define F_SX8  0
#define F_SS8  512
#define F_A1   33280
#define F_C1   33312
#define F_ASC  33344
#define F_CSC  33472
#define F_S2S  33600
#define F_S2Q  33632
#define F_A2   33664
#define F_C2   33696
#define F_SHR  33728
#define F_SS2  33760
#define F_A3   34784
#define F_C3   34912
#define F_CF   35040
#define STATN  35168
#define F_W1B  35200
#define F_CFB  36224
#define F_Y1   38272
#define F_H2   (F_Y1 + NT*16)
#define F_I18  (F_H2 + NT*16)
#define F_WEW  (F_I18 + NV*18)
#define F_WNS  (F_WEW + NV*18)
#define F_XB   (F_WNS + NV*18)

#define FSTR 136

__device__ __forceinline__ float bf2f(ushort_t u) {
    union { unsigned int i; float f; } x; x.i = ((unsigned int)u) << 16; return x.f;
}
__device__ __forceinline__ ushort_t f2bf(float f) {
    union { float f; unsigned int i; } x; x.f = f;
    unsigned int r = x.i + 0x7fffu + ((x.i >> 16) & 1u);
    return (ushort_t)(r >> 16);
}

// ---------------- prep: 18-pt stencil + coeffs->bf16 ----------------
__global__ __launch_bounds__(256) void k_prep(const int* __restrict__ idx_F2V,
                                              const float* __restrict__ vals_F2V,
                                              const int* __restrict__ idx_G,
                                              const float* __restrict__ vals_G,
                                              const float* __restrict__ EW,
                                              const float* __restrict__ NS,
                                              const float* __restrict__ coeffs,
                                              int* __restrict__ i18,
                                              float* __restrict__ wew,
                                              float* __restrict__ wns,
                                              ushort_t* __restrict__ cfb) {
    const int gid = blockIdx.x * 256 + threadIdx.x;
    if (gid < 4096) cfb[gid] = f2bf(coeffs[gid]);
    const int n = gid;
    if (n >= NV) return;
#pragma unroll
    for (int k = 0; k < 6; ++k) {
        int f = idx_F2V[n * 6 + k];
        float fv = vals_F2V[n * 6 + k];
        float e0 = EW[f * 3], e1 = EW[f * 3 + 1], e2 = EW[f * 3 + 2];
        float s0 = NS[f * 3], s1 = NS[f * 3 + 1], s2 = NS[f * 3 + 2];
#pragma unroll
        for (int j = 0; j < 3; ++j) {
            float g0 = vals_G[f * 9 + j], g1 = vals_G[f * 9 + 3 + j], g2 = vals_G[f * 9 + 6 + j];
            i18[n * 18 + k * 3 + j] = idx_G[f * 3 + j];
            wew[n * 18 + k * 3 + j] = fv * (g0 * e0 + g1 * e1 + g2 * e2);
            wns[n * 18 + k * 3 + j] = fv * (g0 * s0 + g1 * s1 + g2 * s2);
        }
    }
}

// ---------------- xcvt: x -> xb (vertex-major bf16) + Sx/SS via reg-resident MFMA SYRK ----------------
__global__ __launch_bounds__(256) void k_xcvt(const float* __restrict__ x,
                                              float* __restrict__ ws,
                                              ushort_t* __restrict__ xb) {
    __shared__ float SSl[64 * 68 + 64];   // block staging: SS (stride 68) + Sx
    const int tid = threadIdx.x;
    const int w = tid >> 6, l = tid & 63;
    const int o16 = l & 15, kg = l >> 4;

    for (int i = tid; i < 64 * 68 + 64; i += 256) SSl[i] = 0.f;
    __syncthreads();

    f32x4 acc[10];    // symmetric tile pairs (mt<=nt)
#pragma unroll
    for (int i = 0; i < 10; ++i) acc[i] = (f32x4){0.f, 0.f, 0.f, 0.f};
    f32x4 accS[4];    // ones-row -> Sx per n-tile
#pragma unroll
    for (int i = 0; i < 4; ++i) accS[i] = (f32x4){0.f, 0.f, 0.f, 0.f};

    bf16x8 onesf;
    {
        short ov = (o16 == 0) ? (short)0x3F80 : (short)0;   // bf16 1.0 on m-row 0
#pragma unroll
        for (int j = 0; j < 8; ++j) onesf[j] = ov;
    }

    const int NCHB = (NV + 63) >> 6;   // 2561 chunks per batch
    const int NW = gridDim.x * 4;
    for (int cid = blockIdx.x * 4 + w; cid < 2 * NCHB; cid += NW) {
        const int b = (cid >= NCHB) ? 1 : 0;
        const int tc = cid - b * NCHB;
        const int n0 = tc << 6;
        const float* xsrc = x + (size_t)b * 64 * NV;
        const bool full = (n0 + 64 <= NV);
        // ---- (a) vertex-per-lane transpose -> xb
        const int n = n0 + l;
        if (n < NV) {
            unsigned int pk[32];
#pragma unroll
            for (int c2 = 0; c2 < 32; ++c2) {
                float f0 = xsrc[(size_t)(2 * c2) * NV + n];
                float f1 = xsrc[(size_t)(2 * c2 + 1) * NV + n];
                pk[c2] = (unsigned int)f2bf(f0) | ((unsigned int)f2bf(f1) << 16);
            }
            ushort_t* row = xb + (size_t)(b * NV + n) * 64;
#pragma unroll
            for (int j = 0; j < 8; ++j) {
                uint4 q = make_uint4(pk[4 * j], pk[4 * j + 1], pk[4 * j + 2], pk[4 * j + 3]);
                *(uint4*)(row + j * 8) = q;
            }
        }
        // ---- (b) ch-major frags straight from global (L1/L2-hot), SYRK
        bf16x8 fr[4][2];
#pragma unroll
        for (int mt = 0; mt < 4; ++mt) {
            const float* rp = xsrc + (size_t)(mt * 16 + o16) * NV + n0;
#pragma unroll
            for (int ks = 0; ks < 2; ++ks) {
                const int v0 = ks * 32 + kg * 8;
                float f[8];
                if (full) {
                    float4 q0 = *(const float4*)(rp + v0);
                    float4 q1 = *(const float4*)(rp + v0 + 4);
                    f[0] = q0.x; f[1] = q0.y; f[2] = q0.z; f[3] = q0.w;
                    f[4] = q1.x; f[5] = q1.y; f[6] = q1.z; f[7] = q1.w;
                } else {
#pragma unroll
                    for (int j = 0; j < 8; ++j)
                        f[j] = (n0 + v0 + j < NV) ? rp[v0 + j] : 0.f;
                }
                bf16x8 fb;
#pragma unroll
                for (int j = 0; j < 8; ++j) fb[j] = (short)f2bf(f[j]);
                fr[mt][ks] = fb;
            }
        }
#pragma unroll
        for (int ks = 0; ks < 2; ++ks) {
            int tt = 0;
#pragma unroll
            for (int mt = 0; mt < 4; ++mt) {
#pragma unroll
                for (int nt2 = 0; nt2 < 4; ++nt2) {
                    if (nt2 >= mt) {
                        acc[tt] = __builtin_amdgcn_mfma_f32_16x16x32_bf16(fr[mt][ks], fr[nt2][ks], acc[tt], 0, 0, 0);
                        ++tt;
                    }
                }
                accS[mt] = __builtin_amdgcn_mfma_f32_16x16x32_bf16(onesf, fr[mt][ks], accS[mt], 0, 0, 0);
            }
        }
    }
    // ---- dump: wave regs -> block LDS atomics
    {
        int tt = 0;
#pragma unroll
        for (int mt = 0; mt < 4; ++mt) {
#pragma unroll
            for (int nt2 = 0; nt2 < 4; ++nt2) {
                if (nt2 >= mt) {
#pragma unroll
                    for (int r = 0; r < 4; ++r) {
                        const int row = mt * 16 + kg * 4 + r;
                        const int col = nt2 * 16 + o16;
                        atomicAdd(&SSl[row * 68 + col], acc[tt][r]);
                    }
                    ++tt;
                }
            }
            if (kg == 0) atomicAdd(&SSl[64 * 68 + mt * 16 + o16], accS[mt][0]);
        }
    }
    __syncthreads();
    // ---- block -> global shard (upper triangle only; fold1 mirrors)
    {
        float* SSg = ws + F_SS8 + (size_t)(blockIdx.x & 7) * 4096;
        for (int i = tid; i < 64 * 64; i += 256) {
            const int r = i >> 6, c = i & 63;
            if (c >= r) {
                float v = SSl[r * 68 + c];
                if (v != 0.f) atomicAdd(&SSg[r * 64 + c], v);
            }
        }
        if (tid < 64) atomicAdd(&ws[F_SX8 + (blockIdx.x & 7) * 64 + tid], SSl[64 * 68 + tid]);
    }
}

// ---------------- fold1: BN1 + BNsc params from x moments (+ w1b bf16 folded) ----------------
__global__ __launch_bounds__(256) void k_fold1(const float* __restrict__ w1,
                                               const float* __restrict__ g1,
                                               const float* __restrict__ be1,
                                               const float* __restrict__ wsc,
                                               const float* __restrict__ gsc,
                                               const float* __restrict__ besc,
                                               float* __restrict__ ws,
                                               ushort_t* __restrict__ w1b) {
    __shared__ float SSl[4096];
    __shared__ float Sxl[64];
    const int tid = threadIdx.x;
    // sum 8 shards (upper triangle), then mirror
    for (int i = tid; i < 4096; i += 256) {
        const int r = i >> 6, c = i & 63;
        float v = 0.f;
        if (c >= r) {
#pragma unroll
            for (int s = 0; s < 8; ++s) v += ws[F_SS8 + s * 4096 + i];
        }
        SSl[i] = v;
    }
    if (tid < 64) {
        float v = 0.f;
#pragma unroll
        for (int s = 0; s < 8; ++s) v += ws[F_SX8 + s * 64 + tid];
        Sxl[tid] = v;
    }
    __syncthreads();
    for (int i = tid; i < 4096; i += 256) {
        const int r = i >> 6, c = i & 63;
        if (c < r) SSl[i] = SSl[c * 64 + r];
    }
    __syncthreads();
    if (tid >= 32) return;
    const int bk = blockIdx.x;
    const float* w;
    float gamma, beta;
    float *pa, *pc;
    if (bk == 0) {
        w = w1 + tid * 64; gamma = g1[tid]; beta = be1[tid];
        pa = ws + F_A1 + tid; pc = ws + F_C1 + tid;
    } else {
        int o = (bk - 1) * 32 + tid;
        w = wsc + o * 64; gamma = gsc[o]; beta = besc[o];
        pa = ws + F_ASC + o; pc = ws + F_CSC + o;
    }
    float4 wr[16];
#pragma unroll
    for (int i = 0; i < 16; ++i) wr[i] = *(const float4*)(w + i * 4);
    float dotm = 0.f, quad = 0.f;
#pragma unroll
    for (int i4 = 0; i4 < 16; ++i4) {
        float4 wi = wr[i4];
        float rd[4] = {0.f, 0.f, 0.f, 0.f};
#pragma unroll
        for (int j4 = 0; j4 < 16; ++j4) {
            float4 wj = wr[j4];
#pragma unroll
            for (int r = 0; r < 4; ++r) {
                const float* row = &SSl[(i4 * 4 + r) * 64 + j4 * 4];
                rd[r] += row[0] * wj.x + row[1] * wj.y + row[2] * wj.z + row[3] * wj.w;
            }
        }
        dotm += wi.x * Sxl[i4 * 4] + wi.y * Sxl[i4 * 4 + 1] + wi.z * Sxl[i4 * 4 + 2] + wi.w * Sxl[i4 * 4 + 3];
        quad += wi.x * rd[0] + wi.y * rd[1] + wi.z * rd[2] + wi.w * rd[3];
    }
    const float invN = 1.0f / (float)NT;
    const float mean0 = dotm * invN;
    const float var = quad * invN - mean0 * mean0;
    const float a = gamma * rsqrtf(var + EPSB);
    *pa = a;
    *pc = beta - a * mean0;
    if (bk == 0) {
#pragma unroll
        for (int i4 = 0; i4 < 16; ++i4) {
            w1b[tid * 64 + i4 * 4 + 0] = f2bf(a * wr[i4].x);
            w1b[tid * 64 + i4 * 4 + 1] = f2bf(a * wr[i4].y);
            w1b[tid * 64 + i4 * 4 + 2] = f2bf(a * wr[i4].z);
            w1b[tid * 64 + i4 * 4 + 3] = f2bf(a * wr[i4].w);
        }
    }
}

// ---------------- conv1 via MFMA: y1[s][32] = relu(w1b . xb[s] + c1) ----------------
__global__ __launch_bounds__(256) void k_conv1(const ushort_t* __restrict__ xb,
                                               const ushort_t* __restrict__ w1b,
                                               const float* __restrict__ ws,
                                               ushort_t* __restrict__ y1) {
    const int tid = threadIdx.x;
    const int w = tid >> 6, l = tid & 63;
    const int o16 = l & 15, kg = l >> 4;
    bf16x8 af[2][2];
#pragma unroll
    for (int mt = 0; mt < 2; ++mt)
#pragma unroll
        for (int ks = 0; ks < 2; ++ks)
            af[mt][ks] = *(const bf16x8*)(w1b + (mt * 16 + o16) * 64 + ks * 32 + kg * 8);
    float c1r[2][4];
#pragma unroll
    for (int mt = 0; mt < 2; ++mt)
#pragma unroll
        for (int r = 0; r < 4; ++r)
            c1r[mt][r] = ws[F_C1 + mt * 16 + kg * 4 + r];

    const int NCH = (NT + 63) >> 6;  // 5121 chunks of 64 verts
    for (int ch = blockIdx.x * 4 + w; ch < NCH; ch += gridDim.x * 4) {
        const int n0 = ch << 6;
        bf16x8 bf[4][2];
#pragma unroll
        for (int nt = 0; nt < 4; ++nt) {
            int row = n0 + nt * 16 + o16;
            row = row < NT ? row : NT - 1;
#pragma unroll
            for (int ks = 0; ks < 2; ++ks)
                bf[nt][ks] = *(const bf16x8*)(xb + (size_t)row * 64 + ks * 32 + kg * 8);
        }
        f32x4 acc[2][4];
#pragma unroll
        for (int mt = 0; mt < 2; ++mt)
#pragma unroll
            for (int nt = 0; nt < 4; ++nt) acc[mt][nt] = (f32x4){0.f, 0.f, 0.f, 0.f};
#pragma unroll
        for (int mt = 0; mt < 2; ++mt)
#pragma unroll
            for (int nt = 0; nt < 4; ++nt)
#pragma unroll
                for (int ks = 0; ks < 2; ++ks)
                    acc[mt][nt] = __builtin_amdgcn_mfma_f32_16x16x32_bf16(af[mt][ks], bf[nt][ks], acc[mt][nt], 0, 0, 0);
#pragma unroll
        for (int nt = 0; nt < 4; ++nt) {
            const int vert = n0 + nt * 16 + o16;
            if (vert < NT) {
#pragma unroll
                for (int mt = 0; mt < 2; ++mt) {
                    uint2 p;
                    p.x = (unsigned)f2bf(fmaxf(acc[mt][nt][0] + c1r[mt][0], 0.f)) |
                          ((unsigned)f2bf(fmaxf(acc[mt][nt][1] + c1r[mt][1], 0.f)) << 16);
                    p.y = (unsigned)f2bf(fmaxf(acc[mt][nt][2] + c1r[mt][2], 0.f)) |
                          ((unsigned)f2bf(fmaxf(acc[mt][nt][3] + c1r[mt][3], 0.f)) << 16);
                    *(uint2*)(y1 + (size_t)vert * 32 + mt * 16 + kg * 4) = p;
                }
            }
        }
    }
}

// ---------------- meshconv v2 (round-8 proven): 2-vertex gathers, wave-uniform metadata ----------------
// lane = (gh = lane>>5: vertex pair half, bh = (lane>>4)&1: batch, c2 = lane&15: channel pair)
__global__ __launch_bounds__(256, 4) void k_meshconv(const ushort_t* __restrict__ y1,
                                                     const ushort_t* __restrict__ cfb,
                                                     const int* __restrict__ idx_L,
                                                     const float* __restrict__ vals_L,
                                                     const int* __restrict__ i18,
                                                     const float* __restrict__ w18ew,
                                                     const float* __restrict__ w18ns,
                                                     ushort_t* __restrict__ h2,
                                                     float* __restrict__ ws) {
    __shared__ __align__(16) ushort_t feat[4][32 * FSTR];
    __shared__ float sred[64];
    const int tid = threadIdx.x;
    const int w = __builtin_amdgcn_readfirstlane(tid >> 6);
    const int lane = tid & 63;
    ushort_t* fw = &feat[w][0];
    const int gh = lane >> 5;
    const int bh = (lane >> 4) & 1;
    const int c2 = lane & 15;
    const int ybase = bh * (NV * 32);
    const int o16 = lane & 15;
    const int kg = lane >> 4;  // 0..3 (MFMA roles)

    if (tid < 64) sred[tid] = 0.f;
    __syncthreads();

    float ssum[8], sssq[8];
#pragma unroll
    for (int i = 0; i < 8; ++i) { ssum[i] = 0.f; sssq[i] = 0.f; }

    const int gw = blockIdx.x * 4 + w;
    const int NW = gridDim.x * 4;
    const int NCH = (NV + 15) >> 4;  // 10241

    for (int ch = gw; ch < NCH; ch += NW) {
        const int n0 = ch << 4;
        // ---- gather: 8 iterations x 2 vertices (gh) x 2 batches (bh) x 16 ch-pairs (c2)
        for (int jj = 0; jj < 8; ++jj) {
            const int gA = 2 * jj;                   // wave-uniform vertex pair
            const int nA = n0 + gA;
            const int nB = nA + 1;
            const int nnA = (nA < NV) ? nA : NV - 1;
            const int nnB = (nB < NV) ? nB : NV - 1;
            const int n = n0 + gA + gh;
            const bool ok = (n < NV);
            const int nn = gh ? nnB : nnA;
            const ushort_t* yb = y1 + ybase;
            // self row (2 channels)
            unsigned int qs = *(const unsigned int*)(yb + (nn << 5) + (c2 << 1));
            float fx0 = bf2f((ushort_t)(qs & 0xffffu));
            float fx1 = bf2f((ushort_t)(qs >> 16));
            float lap0 = 0.f, lap1 = 0.f, ge0 = 0.f, ge1 = 0.f, gn0 = 0.f, gn1 = 0.f;
#pragma unroll
            for (int j = 0; j < 7; ++j) {
                const int viA = idx_L[nnA * 7 + j];
                const int viB = idx_L[nnB * 7 + j];
                const float wvA = vals_L[nnA * 7 + j];
                const float wvB = vals_L[nnB * 7 + j];
                const int vi = gh ? viB : viA;
                const float wv = gh ? wvB : wvA;
                unsigned int q = *(const unsigned int*)(yb + (vi << 5) + (c2 << 1));
                lap0 += wv * bf2f((ushort_t)(q & 0xffffu));
                lap1 += wv * bf2f((ushort_t)(q >> 16));
            }
#pragma unroll
            for (int j = 0; j < 18; ++j) {
                const int viA = i18[nnA * 18 + j];
                const int viB = i18[nnB * 18 + j];
                const float weA = w18ew[nnA * 18 + j];
                const float weB = w18ew[nnB * 18 + j];
                const float wnA = w18ns[nnA * 18 + j];
                const float wnB = w18ns[nnB * 18 + j];
                const int vi = gh ? viB : viA;
                const float we = gh ? weB : weA;
                const float wn = gh ? wnB : wnA;
                unsigned int q = *(const unsigned int*)(yb + (vi << 5) + (c2 << 1));
                float v0 = bf2f((ushort_t)(q & 0xffffu));
                float v1 = bf2f((ushort_t)(q >> 16));
                ge0 += we * v0; ge1 += we * v1;
                gn0 += wn * v0; gn1 += wn * v1;
            }
            unsigned int u0 = 0u, u1 = 0u, u2 = 0u, u3 = 0u;
            if (ok) {
                u0 = (unsigned int)f2bf(fx0) | ((unsigned int)f2bf(lap0) << 16);
                u1 = (unsigned int)f2bf(ge0) | ((unsigned int)f2bf(gn0) << 16);
                u2 = (unsigned int)f2bf(fx1) | ((unsigned int)f2bf(lap1) << 16);
                u3 = (unsigned int)f2bf(ge1) | ((unsigned int)f2bf(gn1) << 16);
            }
            const int inst = bh * 16 + gA + gh;
            *(uint4*)(fw + inst * FSTR + (c2 << 3)) = make_uint4(u0, u1, u2, u3);
        }
        // ---- MFMA phase: D[o=32][inst=32] = coeffs[32x128] * feat[128x32]
        f32x4 acc[2][2];
#pragma unroll
        for (int mt = 0; mt < 2; ++mt)
#pragma unroll
            for (int nt = 0; nt < 2; ++nt) acc[mt][nt] = (f32x4){0.f, 0.f, 0.f, 0.f};
        bf16x8 bfr[2][4];
#pragma unroll
        for (int nt = 0; nt < 2; ++nt)
#pragma unroll
            for (int kt = 0; kt < 4; ++kt)
                bfr[nt][kt] = *(const bf16x8*)(fw + (nt * 16 + o16) * FSTR + kt * 32 + kg * 8);
#pragma unroll
        for (int mt = 0; mt < 2; ++mt) {
#pragma unroll
            for (int kt = 0; kt < 4; ++kt) {
                bf16x8 af = *(const bf16x8*)(cfb + (mt * 16 + o16) * 128 + kt * 32 + kg * 8);
                acc[mt][0] = __builtin_amdgcn_mfma_f32_16x16x32_bf16(af, bfr[0][kt], acc[mt][0], 0, 0, 0);
                acc[mt][1] = __builtin_amdgcn_mfma_f32_16x16x32_bf16(af, bfr[1][kt], acc[mt][1], 0, 0, 0);
            }
        }
        // ---- write h2 (bf16) + accumulate bn2 stats
        const int n = n0 + o16;
        if (n < NV) {
#pragma unroll
            for (int nt = 0; nt < 2; ++nt) {
                const int rowb = ((nt * NV + n) << 5);
#pragma unroll
                for (int mt = 0; mt < 2; ++mt) {
#pragma unroll
                    for (int r = 0; r < 4; ++r) {
                        float v = acc[mt][nt][r];
                        int o = mt * 16 + kg * 4 + r;
                        h2[rowb + o] = f2bf(v);
                        ssum[mt * 4 + r] += v;
                        sssq[mt * 4 + r] += v * v;
                    }
                }
            }
        }
    }

#pragma unroll
    for (int si = 0; si < 8; ++si) {
#pragma unroll
        for (int m = 1; m < 16; m <<= 1) {
            ssum[si] += __shfl_xor(ssum[si], m, 16);
            sssq[si] += __shfl_xor(sssq[si], m, 16);
        }
    }
    if (o16 == 0) {
#pragma unroll
        for (int mt = 0; mt < 2; ++mt)
#pragma unroll
            for (int r = 0; r < 4; ++r) {
                int o = mt * 16 + kg * 4 + r;
                atomicAdd(&sred[o], ssum[mt * 4 + r]);
                atomicAdd(&sred[32 + o], sssq[mt * 4 + r]);
            }
    }
    __syncthreads();
    if (tid < 64) atomicAdd(&ws[F_S2S + tid], sred[tid]);
}

// ---------------- hr moments (fold2 fused as prologue) ----------------
__global__ __launch_bounds__(256) void k_hrmoments(const ushort_t* __restrict__ h2,
                                                   const float* __restrict__ g2,
                                                   const float* __restrict__ be2,
                                                   float* __restrict__ ws) {
    __shared__ __align__(16) ushort_t tile[4][32 * 40];
    __shared__ float red[1056];
    __shared__ float sA2[32], sC2[32];
    const int tid = threadIdx.x;
    const int w = tid >> 6, l = tid & 63;
    ushort_t* T = &tile[w][0];
    const int c8 = (l & 3) * 8;
    const int v0 = l >> 2;
    const int fr = l & 15, kg = l >> 4;

    if (tid < 32) {
        const float invN = 1.0f / (float)NT;
        float m = ws[F_S2S + tid] * invN;
        float var = ws[F_S2Q + tid] * invN - m * m;
        float a = g2[tid] * rsqrtf(var + EPSB);
        float c = be2[tid] - a * m;
        sA2[tid] = a; sC2[tid] = c;
        ws[F_A2 + tid] = a; ws[F_C2 + tid] = c;   // all blocks write identical values
    }
    for (int i = tid; i < 1056; i += 256) red[i] = 0.f;
    __syncthreads();

    float a2r[8], c2r[8];
#pragma unroll
    for (int j = 0; j < 8; ++j) { a2r[j] = sA2[c8 + j]; c2r[j] = sC2[c8 + j]; }

    f32x4 acc[2][2];
#pragma unroll
    for (int a = 0; a < 2; ++a)
#pragma unroll
        for (int b = 0; b < 2; ++b) acc[a][b] = (f32x4){0.f, 0.f, 0.f, 0.f};
    float ssum[8];
#pragma unroll
    for (int j = 0; j < 8; ++j) ssum[j] = 0.f;

    const int NCH = (NT + 31) >> 5;
    for (int ch = blockIdx.x * 4 + w; ch < NCH; ch += gridDim.x * 4) {
        const int s0 = ch << 5;
#pragma unroll
        for (int i = 0; i < 2; ++i) {
            const int vert = i * 16 + v0;
            const int s = s0 + vert;
            uint4 q = make_uint4(0u, 0u, 0u, 0u);
            const bool ok = (s < NT);
            if (ok) q = *(const uint4*)(h2 + (size_t)s * 32 + c8);
            const ushort_t* qs = (const ushort_t*)&q;
            ushort_t hb[8];
#pragma unroll
            for (int j = 0; j < 8; ++j) {
                float hv = ok ? fmaxf(a2r[j] * bf2f(qs[j]) + c2r[j], 0.f) : 0.f;
                ssum[j] += hv;
                hb[j] = f2bf(hv);
            }
#pragma unroll
            for (int j = 0; j < 8; ++j) T[(c8 + j) * 40 + vert] = hb[j];
        }
        bf16x8 f0 = *(const bf16x8*)(T + fr * 40 + kg * 8);
        bf16x8 f1 = *(const bf16x8*)(T + (16 + fr) * 40 + kg * 8);
        acc[0][0] = __builtin_amdgcn_mfma_f32_16x16x32_bf16(f0, f0, acc[0][0], 0, 0, 0);
        acc[0][1] = __builtin_amdgcn_mfma_f32_16x16x32_bf16(f0, f1, acc[0][1], 0, 0, 0);
        acc[1][0] = __builtin_amdgcn_mfma_f32_16x16x32_bf16(f1, f0, acc[1][0], 0, 0, 0);
        acc[1][1] = __builtin_amdgcn_mfma_f32_16x16x32_bf16(f1, f1, acc[1][1], 0, 0, 0);
    }
#pragma unroll
    for (int mt = 0; mt < 2; ++mt)
#pragma unroll
        for (int nt = 0; nt < 2; ++nt)
#pragma unroll
            for (int r = 0; r < 4; ++r)
                atomicAdd(&red[(mt * 16 + kg * 4 + r) * 32 + nt * 16 + fr], acc[mt][nt][r]);
#pragma unroll
    for (int j = 0; j < 8; ++j) {
        float s = ssum[j];
        s += __shfl_xor(s, 4); s += __shfl_xor(s, 8);
        s += __shfl_xor(s, 16); s += __shfl_xor(s, 32);
        if (v0 == 0) atomicAdd(&red[1024 + c8 + j], s);
    }
    __syncthreads();
    for (int i = tid; i < 1024; i += 256) atomicAdd(&ws[F_SS2 + i], red[i]);
    if (tid < 32) atomicAdd(&ws[F_SHR + tid], red[1024 + tid]);
}

// ---------------- fold3: BN3 params + fused final weights Wf (bf16) ----------------
__global__ __launch_bounds__(128) void k_fold3(const float* __restrict__ w3,
                                               const float* __restrict__ wsc,
                                               const float* __restrict__ g3,
                                               const float* __restrict__ be3,
                                               float* __restrict__ ws,
                                               ushort_t* __restrict__ wfb) {
    __shared__ float SSl[1024];
    __shared__ float Sl[32];
    const int tid = threadIdx.x;
    for (int i = tid; i < 1024; i += 128) SSl[i] = ws[F_SS2 + i];
    if (tid < 32) Sl[tid] = ws[F_SHR + tid];
    __syncthreads();
    const int o = tid;
    float4 wr[8];
#pragma unroll
    for (int i = 0; i < 8; ++i) wr[i] = *(const float4*)(w3 + o * 32 + i * 4);
    float dotm = 0.f, quad = 0.f;
#pragma unroll
    for (int i4 = 0; i4 < 8; ++i4) {
        float4 wi = wr[i4];
        float rd[4] = {0.f, 0.f, 0.f, 0.f};
#pragma unroll
        for (int j4 = 0; j4 < 8; ++j4) {
            float4 wj = wr[j4];
#pragma unroll
            for (int r = 0; r < 4; ++r) {
                const float* row = &SSl[(i4 * 4 + r) * 32 + j4 * 4];
                rd[r] += row[0] * wj.x + row[1] * wj.y + row[2] * wj.z + row[3] * wj.w;
            }
        }
        dotm += wi.x * Sl[i4 * 4] + wi.y * Sl[i4 * 4 + 1] + wi.z * Sl[i4 * 4 + 2] + wi.w * Sl[i4 * 4 + 3];
        quad += wi.x * rd[0] + wi.y * rd[1] + wi.z * rd[2] + wi.w * rd[3];
    }
    const float invN = 1.0f / (float)NT;
    const float mean0 = dotm * invN;
    const float var = quad * invN - mean0 * mean0;
    const float a = g3[o] * rsqrtf(var + EPSB);
    const float cbias = be3[o] - a * mean0;
    ws[F_A3 + o] = a;
    ws[F_C3 + o] = cbias;
    const float asc = ws[F_ASC + o], csc = ws[F_CSC + o];
    ws[F_CF + o] = cbias + csc;
#pragma unroll
    for (int i4 = 0; i4 < 8; ++i4) {
        wfb[o * 96 + i4 * 4 + 0] = f2bf(a * wr[i4].x);
        wfb[o * 96 + i4 * 4 + 1] = f2bf(a * wr[i4].y);
        wfb[o * 96 + i4 * 4 + 2] = f2bf(a * wr[i4].z);
        wfb[o * 96 + i4 * 4 + 3] = f2bf(a * wr[i4].w);
    }
    for (int j = 0; j < 64; ++j)
        wfb[o * 96 + 32 + j] = f2bf(asc * wsc[o * 64 + j]);
}

// ---------------- final: fused [conv3+bn3 | conv_sc+bn_sc] MFMA GEMM + relu (direct stores) ----------------
__global__ __launch_bounds__(256) void k_final(const ushort_t* __restrict__ xb,
                                               const ushort_t* __restrict__ h2,
                                               const ushort_t* __restrict__ wfb,
                                               const float* __restrict__ ws,
                                               float* __restrict__ out) {
    __shared__ __align__(16) ushort_t feat[32 * 104];
    const int tid = threadIdx.x;
    const int w = tid >> 6, l = tid & 63;
    const int fr = l & 15, kg = l >> 4;

    bf16x8 af[2][3];
#pragma unroll
    for (int mt = 0; mt < 2; ++mt)
#pragma unroll
        for (int kt = 0; kt < 3; ++kt)
            af[mt][kt] = *(const bf16x8*)(wfb + (w * 32 + mt * 16 + fr) * 96 + kt * 32 + kg * 8);
    float cfr[2][4];
#pragma unroll
    for (int mt = 0; mt < 2; ++mt)
#pragma unroll
        for (int r = 0; r < 4; ++r)
            cfr[mt][r] = ws[F_CF + w * 32 + mt * 16 + kg * 4 + r];

    const int hv = tid >> 3, hc4 = (tid & 7) * 4;
    float a2r[4], c2r[4];
#pragma unroll
    for (int j = 0; j < 4; ++j) { a2r[j] = ws[F_A2 + hc4 + j]; c2r[j] = ws[F_C2 + hc4 + j]; }
    const int xv = tid >> 3, xseg = tid & 7;

    const int NCHK = (NV + 31) >> 5;  // 5121
    for (int cid = blockIdx.x; cid < 2 * NCHK; cid += gridDim.x) {
        const int b = (cid >= NCHK) ? 1 : 0;
        const int t = cid - b * NCHK;
        const int n0 = t << 5;
        const int rem = NV - n0 < 32 ? NV - n0 : 32;
        {
            const int s = b * NV + n0 + hv;
            const bool ok = (hv < rem);
            uint2 q = make_uint2(0u, 0u);
            if (ok) q = *(const uint2*)(h2 + (size_t)s * 32 + hc4);
            const ushort_t* qs = (const ushort_t*)&q;
            unsigned int p0 = 0u, p1 = 0u;
            if (ok) {
                float h0 = fmaxf(a2r[0] * bf2f(qs[0]) + c2r[0], 0.f);
                float h1 = fmaxf(a2r[1] * bf2f(qs[1]) + c2r[1], 0.f);
                float h2v = fmaxf(a2r[2] * bf2f(qs[2]) + c2r[2], 0.f);
                float h3 = fmaxf(a2r[3] * bf2f(qs[3]) + c2r[3], 0.f);
                p0 = (unsigned int)f2bf(h0) | ((unsigned int)f2bf(h1) << 16);
                p1 = (unsigned int)f2bf(h2v) | ((unsigned int)f2bf(h3) << 16);
            }
            *(uint2*)(feat + hv * 104 + hc4) = make_uint2(p0, p1);
        }
        {
            const int s = b * NV + n0 + xv;
            uint4 q = make_uint4(0u, 0u, 0u, 0u);
            if (xv < rem) q = *(const uint4*)(xb + (size_t)s * 64 + xseg * 8);
            *(uint4*)(feat + xv * 104 + 32 + xseg * 8) = q;
        }
        __syncthreads();
        bf16x8 bf[2][3];
#pragma unroll
        for (int nt = 0; nt < 2; ++nt)
#pragma unroll
            for (int kt = 0; kt < 3; ++kt)
                bf[nt][kt] = *(const bf16x8*)(feat + (nt * 16 + fr) * 104 + kt * 32 + kg * 8);
        __syncthreads();
        f32x4 acc[2][2];
#pragma unroll
        for (int mt = 0; mt < 2; ++mt)
#pragma unroll
            for (int nt = 0; nt < 2; ++nt) acc[mt][nt] = (f32x4){0.f, 0.f, 0.f, 0.f};
#pragma unroll
        for (int mt = 0; mt < 2; ++mt)
#pragma unroll
            for (int nt = 0; nt < 2; ++nt)
#pragma unroll
                for (int kt = 0; kt < 3; ++kt)
                    acc[mt][nt] = __builtin_amdgcn_mfma_f32_16x16x32_bf16(af[mt][kt], bf[nt][kt], acc[mt][nt], 0, 0, 0);
#pragma unroll
        for (int mt = 0; mt < 2; ++mt) {
#pragma unroll
            for (int nt = 0; nt < 2; ++nt) {
                const int col = n0 + nt * 16 + fr;
                if (col < NV) {
                    float* po = out + (size_t)(b * 128 + w * 32 + mt * 16 + kg * 4) * NV + col;
#pragma unroll
                    for (int r = 0; r < 4; ++r)
                        po[(size_t)r * NV] = fmaxf(acc[mt][nt][r] + cfr[mt][r], 0.f);
                }
            }
        }
    }
}

extern "C" void kernel_launch(void* const* d_in, const int* in_sizes, int n_in,
                              void* d_out, int out_size, void* d_ws, size_t ws_size,
                              hipStream_t stream) {
    (void)in_sizes; (void)n_in; (void)out_size; (void)ws_size;
    const float* x        = (const float*)d_in[0];
    const float* w1       = (const float*)d_in[1];
    const float* g1       = (const float*)d_in[3];
    const float* be1      = (const float*)d_in[4];
    const float* coeffs   = (const float*)d_in[5];
    const float* g2       = (const float*)d_in[7];
    const float* be2      = (const float*)d_in[8];
    const float* w3       = (const float*)d_in[9];
    const float* g3       = (const float*)d_in[11];
    const float* be3      = (const float*)d_in[12];
    const float* wsc      = (const float*)d_in[13];
    const float* gsc      = (const float*)d_in[15];
    const float* besc     = (const float*)d_in[16];
    const int*   idx_G    = (const int*)d_in[17];
    const float* vals_G   = (const float*)d_in[18];
    const float* EW       = (const float*)d_in[19];
    const float* NS       = (const float*)d_in[20];
    const int*   idx_L    = (const int*)d_in[21];
    const float* vals_L   = (const float*)d_in[22];
    const int*   idx_F2V  = (const int*)d_in[23];
    const float* vals_F2V = (const float*)d_in[24];
    float* ws  = (float*)d_ws;
    float* out = (float*)d_out;

    ushort_t* w1b = (ushort_t*)(ws + F_W1B);
    ushort_t* cfb = (ushort_t*)(ws + F_CFB);
    ushort_t* y1  = (ushort_t*)(ws + F_Y1);
    ushort_t* h2  = (ushort_t*)(ws + F_H2);
    ushort_t* xb  = (ushort_t*)(ws + F_XB);
    ushort_t* wfb = (ushort_t*)(ws + F_Y1);  // aliases y1 (dead after meshconv)

    hipMemsetAsync(ws, 0, STATN * sizeof(float), stream);
    hipLaunchKernelGGL(k_prep, dim3((NV + 255) / 256), dim3(256), 0, stream,
                       idx_F2V, vals_F2V, idx_G, vals_G, EW, NS, coeffs,
                       (int*)(ws + F_I18), ws + F_WEW, ws + F_WNS, cfb);
    hipLaunchKernelGGL(k_xcvt, dim3(1280), dim3(256), 0, stream, x, ws, xb);
    hipLaunchKernelGGL(k_fold1, dim3(5), dim3(256), 0, stream, w1, g1, be1, wsc, gsc, besc, ws, w1b);
    hipLaunchKernelGGL(k_conv1, dim3(1280), dim3(256), 0, stream, xb, w1b, ws, y1);
    hipLaunchKernelGGL(k_meshconv, dim3(1024), dim3(256), 0, stream,
                       y1, cfb, idx_L, vals_L,
                       (const int*)(ws + F_I18), ws + F_WEW, ws + F_WNS,
                       h2, ws);
    hipLaunchKernelGGL(k_hrmoments, dim3(1024), dim3(256), 0, stream, h2, g2, be2, ws);
    hipLaunchKernelGGL(k_fold3, dim3(1), dim3(128), 0, stream, w3, wsc, g3, be3, ws, wfb);
    hipLaunchKernelGGL(k_final, dim3(2048), dim3(256), 0, stream, xb, h2, wfb, ws, out);
}

// Round 12
// 510.418 us; speedup vs baseline: 1.4080x; 1.0546x over previous
//
#include <hip/hip_runtime.h>

#define NV   163842
#define NF   327680
#define BB   2
#define INC  64
#define NECK 32
#define OUTC 128
#define NT   (BB*NV)
#define EPSB 1e-5f

typedef unsigned short ushort_t;
typedef __attribute__((ext_vector_type(8))) short bf16x8;
typedef __attribute__((ext_vector_type(4))) float f32x4;

// workspace float offsets
#define F_SX8  0
#define F_SS8  512
#define F_A1   33280
#define F_C1   33312
#define F_ASC  33344
#define F_CSC  33472
#define F_S2S  33600
#define F_S2Q  33632
#define F_A2   33664
#define F_C2   33696
#define F_SHR  33728
#define F_SS2  33760
#define F_A3   34784
#define F_C3   34912
#define F_CF   35040
#define STATN  35168
#define F_W1B  35200
#define F_CFB  36224
#define F_Y1   38272
#define F_H2   (F_Y1 + NT*16)
#define F_I18  (F_H2 + NT*16)
#define F_WEW  (F_I18 + NV*18)
#define F_WNS  (F_WEW + NV*18)
#define F_XB   (F_WNS + NV*18)
// face records (NF x 16 floats = 21 MB) alias the xb region: consumed by k_prep
// strictly before k_xcvt writes xb.

#define FSTR 136

__device__ __forceinline__ float bf2f(ushort_t u) {
    union { unsigned int i; float f; } x; x.i = ((unsigned int)u) << 16; return x.f;
}
__device__ __forceinline__ ushort_t f2bf(float f) {
    union { float f; unsigned int i; } x; x.f = f;
    unsigned int r = x.i + 0x7fffu + ((x.i >> 16) & 1u);
    return (ushort_t)(r >> 16);
}

// ---------------- face: per-face 64B record {i0,i1,i2,gE[3],gN[3]} (sequential) ----------------
__global__ __launch_bounds__(256) void k_face(const int* __restrict__ idx_G,
                                              const float* __restrict__ vals_G,
                                              const float* __restrict__ EW,
                                              const float* __restrict__ NS,
                                              float* __restrict__ frec) {
    const int f = blockIdx.x * 256 + threadIdx.x;
    if (f >= NF) return;
    const float e0 = EW[f * 3], e1 = EW[f * 3 + 1], e2 = EW[f * 3 + 2];
    const float s0 = NS[f * 3], s1 = NS[f * 3 + 1], s2 = NS[f * 3 + 2];
    const int i0 = idx_G[f * 3], i1 = idx_G[f * 3 + 1], i2 = idx_G[f * 3 + 2];
    float gE[3], gN[3];
#pragma unroll
    for (int j = 0; j < 3; ++j) {
        const float g0 = vals_G[f * 9 + j], g1 = vals_G[f * 9 + 3 + j], g2 = vals_G[f * 9 + 6 + j];
        gE[j] = g0 * e0 + g1 * e1 + g2 * e2;
        gN[j] = g0 * s0 + g1 * s1 + g2 * s2;
    }
    float* r = frec + (size_t)f * 16;
    float4 q0, q1, q2;
    q0.x = __int_as_float(i0); q0.y = __int_as_float(i1); q0.z = __int_as_float(i2); q0.w = gE[0];
    q1.x = gE[1]; q1.y = gE[2]; q1.z = gN[0]; q1.w = gN[1];
    q2.x = gN[2]; q2.y = 0.f; q2.z = 0.f; q2.w = 0.f;
    *(float4*)(r + 0) = q0;
    *(float4*)(r + 4) = q1;
    *(float4*)(r + 8) = q2;
}

// ---------------- prep v2: 18-pt stencil from face records (1 line/tap) + coeffs->bf16 ----------------
__global__ __launch_bounds__(256) void k_prep(const int* __restrict__ idx_F2V,
                                              const float* __restrict__ vals_F2V,
                                              const float* __restrict__ frec,
                                              const float* __restrict__ coeffs,
                                              int* __restrict__ i18,
                                              float* __restrict__ wew,
                                              float* __restrict__ wns,
                                              ushort_t* __restrict__ cfb) {
    const int gid = blockIdx.x * 256 + threadIdx.x;
    if (gid < 4096) cfb[gid] = f2bf(coeffs[gid]);
    const int n = gid;
    if (n >= NV) return;
#pragma unroll
    for (int k = 0; k < 6; ++k) {
        const int f = idx_F2V[n * 6 + k];
        const float fv = vals_F2V[n * 6 + k];
        const float* r = frec + (size_t)f * 16;
        float4 q0 = *(const float4*)(r + 0);
        float4 q1 = *(const float4*)(r + 4);
        float gN2 = r[8];
        i18[n * 18 + k * 3 + 0] = __float_as_int(q0.x);
        i18[n * 18 + k * 3 + 1] = __float_as_int(q0.y);
        i18[n * 18 + k * 3 + 2] = __float_as_int(q0.z);
        wew[n * 18 + k * 3 + 0] = fv * q0.w;
        wew[n * 18 + k * 3 + 1] = fv * q1.x;
        wew[n * 18 + k * 3 + 2] = fv * q1.y;
        wns[n * 18 + k * 3 + 0] = fv * q1.z;
        wns[n * 18 + k * 3 + 1] = fv * q1.w;
        wns[n * 18 + k * 3 + 2] = fv * gN2;
    }
}

// ---------------- xcvt: x -> xb (vertex-major bf16) + Sx/SS via reg-resident MFMA SYRK ----------------
__global__ __launch_bounds__(256) void k_xcvt(const float* __restrict__ x,
                                              float* __restrict__ ws,
                                              ushort_t* __restrict__ xb) {
    __shared__ float SSl[64 * 68 + 64];   // block staging: SS (stride 68) + Sx
    const int tid = threadIdx.x;
    const int w = tid >> 6, l = tid & 63;
    const int o16 = l & 15, kg = l >> 4;

    for (int i = tid; i < 64 * 68 + 64; i += 256) SSl[i] = 0.f;
    __syncthreads();

    f32x4 acc[10];    // symmetric tile pairs (mt<=nt)
#pragma unroll
    for (int i = 0; i < 10; ++i) acc[i] = (f32x4){0.f, 0.f, 0.f, 0.f};
    f32x4 accS[4];    // ones-row -> Sx per n-tile
#pragma unroll
    for (int i = 0; i < 4; ++i) accS[i] = (f32x4){0.f, 0.f, 0.f, 0.f};

    bf16x8 onesf;
    {
        short ov = (o16 == 0) ? (short)0x3F80 : (short)0;   // bf16 1.0 on m-row 0
#pragma unroll
        for (int j = 0; j < 8; ++j) onesf[j] = ov;
    }

    const int NCHB = (NV + 63) >> 6;   // 2561 chunks per batch
    const int NW = gridDim.x * 4;
    for (int cid = blockIdx.x * 4 + w; cid < 2 * NCHB; cid += NW) {
        const int b = (cid >= NCHB) ? 1 : 0;
        const int tc = cid - b * NCHB;
        const int n0 = tc << 6;
        const float* xsrc = x + (size_t)b * 64 * NV;
        const bool full = (n0 + 64 <= NV);
        // ---- (a) vertex-per-lane transpose -> xb
        const int n = n0 + l;
        if (n < NV) {
            unsigned int pk[32];
#pragma unroll
            for (int c2 = 0; c2 < 32; ++c2) {
                float f0 = xsrc[(size_t)(2 * c2) * NV + n];
                float f1 = xsrc[(size_t)(2 * c2 + 1) * NV + n];
                pk[c2] = (unsigned int)f2bf(f0) | ((unsigned int)f2bf(f1) << 16);
            }
            ushort_t* row = xb + (size_t)(b * NV + n) * 64;
#pragma unroll
            for (int j = 0; j < 8; ++j) {
                uint4 q = make_uint4(pk[4 * j], pk[4 * j + 1], pk[4 * j + 2], pk[4 * j + 3]);
                *(uint4*)(row + j * 8) = q;
            }
        }
        // ---- (b) ch-major frags straight from global (L1/L2-hot), SYRK
        bf16x8 fr[4][2];
#pragma unroll
        for (int mt = 0; mt < 4; ++mt) {
            const float* rp = xsrc + (size_t)(mt * 16 + o16) * NV + n0;
#pragma unroll
            for (int ks = 0; ks < 2; ++ks) {
                const int v0 = ks * 32 + kg * 8;
                float f[8];
                if (full) {
                    float4 q0 = *(const float4*)(rp + v0);
                    float4 q1 = *(const float4*)(rp + v0 + 4);
                    f[0] = q0.x; f[1] = q0.y; f[2] = q0.z; f[3] = q0.w;
                    f[4] = q1.x; f[5] = q1.y; f[6] = q1.z; f[7] = q1.w;
                } else {
#pragma unroll
                    for (int j = 0; j < 8; ++j)
                        f[j] = (n0 + v0 + j < NV) ? rp[v0 + j] : 0.f;
                }
                bf16x8 fb;
#pragma unroll
                for (int j = 0; j < 8; ++j) fb[j] = (short)f2bf(f[j]);
                fr[mt][ks] = fb;
            }
        }
#pragma unroll
        for (int ks = 0; ks < 2; ++ks) {
            int tt = 0;
#pragma unroll
            for (int mt = 0; mt < 4; ++mt) {
#pragma unroll
                for (int nt2 = 0; nt2 < 4; ++nt2) {
                    if (nt2 >= mt) {
                        acc[tt] = __builtin_amdgcn_mfma_f32_16x16x32_bf16(fr[mt][ks], fr[nt2][ks], acc[tt], 0, 0, 0);
                        ++tt;
                    }
                }
                accS[mt] = __builtin_amdgcn_mfma_f32_16x16x32_bf16(onesf, fr[mt][ks], accS[mt], 0, 0, 0);
            }
        }
    }
    // ---- dump: wave regs -> block LDS atomics
    {
        int tt = 0;
#pragma unroll
        for (int mt = 0; mt < 4; ++mt) {
#pragma unroll
            for (int nt2 = 0; nt2 < 4; ++nt2) {
                if (nt2 >= mt) {
#pragma unroll
                    for (int r = 0; r < 4; ++r) {
                        const int row = mt * 16 + kg * 4 + r;
                        const int col = nt2 * 16 + o16;
                        atomicAdd(&SSl[row * 68 + col], acc[tt][r]);
                    }
                    ++tt;
                }
            }
            if (kg == 0) atomicAdd(&SSl[64 * 68 + mt * 16 + o16], accS[mt][0]);
        }
    }
    __syncthreads();
    // ---- block -> global shard (upper triangle only; fold1 mirrors)
    {
        float* SSg = ws + F_SS8 + (size_t)(blockIdx.x & 7) * 4096;
        for (int i = tid; i < 64 * 64; i += 256) {
            const int r = i >> 6, c = i & 63;
            if (c >= r) {
                float v = SSl[r * 68 + c];
                if (v != 0.f) atomicAdd(&SSg[r * 64 + c], v);
            }
        }
        if (tid < 64) atomicAdd(&ws[F_SX8 + (blockIdx.x & 7) * 64 + tid], SSl[64 * 68 + tid]);
    }
}

// ---------------- fold1: BN1 + BNsc params from x moments (+ w1b bf16 folded) ----------------
__global__ __launch_bounds__(256) void k_fold1(const float* __restrict__ w1,
                                               const float* __restrict__ g1,
                                               const float* __restrict__ be1,
                                               const float* __restrict__ wsc,
                                               const float* __restrict__ gsc,
                                               const float* __restrict__ besc,
                                               float* __restrict__ ws,
                                               ushort_t* __restrict__ w1b) {
    __shared__ float SSl[4096];
    __shared__ float Sxl[64];
    const int tid = threadIdx.x;
    // sum 8 shards (upper triangle), then mirror
    for (int i = tid; i < 4096; i += 256) {
        const int r = i >> 6, c = i & 63;
        float v = 0.f;
        if (c >= r) {
#pragma unroll
            for (int s = 0; s < 8; ++s) v += ws[F_SS8 + s * 4096 + i];
        }
        SSl[i] = v;
    }
    if (tid < 64) {
        float v = 0.f;
#pragma unroll
        for (int s = 0; s < 8; ++s) v += ws[F_SX8 + s * 64 + tid];
        Sxl[tid] = v;
    }
    __syncthreads();
    for (int i = tid; i < 4096; i += 256) {
        const int r = i >> 6, c = i & 63;
        if (c < r) SSl[i] = SSl[c * 64 + r];
    }
    __syncthreads();
    if (tid >= 32) return;
    const int bk = blockIdx.x;
    const float* w;
    float gamma, beta;
    float *pa, *pc;
    if (bk == 0) {
        w = w1 + tid * 64; gamma = g1[tid]; beta = be1[tid];
        pa = ws + F_A1 + tid; pc = ws + F_C1 + tid;
    } else {
        int o = (bk - 1) * 32 + tid;
        w = wsc + o * 64; gamma = gsc[o]; beta = besc[o];
        pa = ws + F_ASC + o; pc = ws + F_CSC + o;
    }
    float4 wr[16];
#pragma unroll
    for (int i = 0; i < 16; ++i) wr[i] = *(const float4*)(w + i * 4);
    float dotm = 0.f, quad = 0.f;
#pragma unroll
    for (int i4 = 0; i4 < 16; ++i4) {
        float4 wi = wr[i4];
        float rd[4] = {0.f, 0.f, 0.f, 0.f};
#pragma unroll
        for (int j4 = 0; j4 < 16; ++j4) {
            float4 wj = wr[j4];
#pragma unroll
            for (int r = 0; r < 4; ++r) {
                const float* row = &SSl[(i4 * 4 + r) * 64 + j4 * 4];
                rd[r] += row[0] * wj.x + row[1] * wj.y + row[2] * wj.z + row[3] * wj.w;
            }
        }
        dotm += wi.x * Sxl[i4 * 4] + wi.y * Sxl[i4 * 4 + 1] + wi.z * Sxl[i4 * 4 + 2] + wi.w * Sxl[i4 * 4 + 3];
        quad += wi.x * rd[0] + wi.y * rd[1] + wi.z * rd[2] + wi.w * rd[3];
    }
    const float invN = 1.0f / (float)NT;
    const float mean0 = dotm * invN;
    const float var = quad * invN - mean0 * mean0;
    const float a = gamma * rsqrtf(var + EPSB);
    *pa = a;
    *pc = beta - a * mean0;
    if (bk == 0) {
#pragma unroll
        for (int i4 = 0; i4 < 16; ++i4) {
            w1b[tid * 64 + i4 * 4 + 0] = f2bf(a * wr[i4].x);
            w1b[tid * 64 + i4 * 4 + 1] = f2bf(a * wr[i4].y);
            w1b[tid * 64 + i4 * 4 + 2] = f2bf(a * wr[i4].z);
            w1b[tid * 64 + i4 * 4 + 3] = f2bf(a * wr[i4].w);
        }
    }
}

// ---------------- conv1 via MFMA: y1[s][32] = relu(w1b . xb[s] + c1) ----------------
__global__ __launch_bounds__(256) void k_conv1(const ushort_t* __restrict__ xb,
                                               const ushort_t* __restrict__ w1b,
                                               const float* __restrict__ ws,
                                               ushort_t* __restrict__ y1) {
    const int tid = threadIdx.x;
    const int w = tid >> 6, l = tid & 63;
    const int o16 = l & 15, kg = l >> 4;
    bf16x8 af[2][2];
#pragma unroll
    for (int mt = 0; mt < 2; ++mt)
#pragma unroll
        for (int ks = 0; ks < 2; ++ks)
            af[mt][ks] = *(const bf16x8*)(w1b + (mt * 16 + o16) * 64 + ks * 32 + kg * 8);
    float c1r[2][4];
#pragma unroll
    for (int mt = 0; mt < 2; ++mt)
#pragma unroll
        for (int r = 0; r < 4; ++r)
            c1r[mt][r] = ws[F_C1 + mt * 16 + kg * 4 + r];

    const int NCH = (NT + 63) >> 6;  // 5121 chunks of 64 verts
    for (int ch = blockIdx.x * 4 + w; ch < NCH; ch += gridDim.x * 4) {
        const int n0 = ch << 6;
        bf16x8 bf[4][2];
#pragma unroll
        for (int nt = 0; nt < 4; ++nt) {
            int row = n0 + nt * 16 + o16;
            row = row < NT ? row : NT - 1;
#pragma unroll
            for (int ks = 0; ks < 2; ++ks)
                bf[nt][ks] = *(const bf16x8*)(xb + (size_t)row * 64 + ks * 32 + kg * 8);
        }
        f32x4 acc[2][4];
#pragma unroll
        for (int mt = 0; mt < 2; ++mt)
#pragma unroll
            for (int nt = 0; nt < 4; ++nt) acc[mt][nt] = (f32x4){0.f, 0.f, 0.f, 0.f};
#pragma unroll
        for (int mt = 0; mt < 2; ++mt)
#pragma unroll
            for (int nt = 0; nt < 4; ++nt)
#pragma unroll
                for (int ks = 0; ks < 2; ++ks)
                    acc[mt][nt] = __builtin_amdgcn_mfma_f32_16x16x32_bf16(af[mt][ks], bf[nt][ks], acc[mt][nt], 0, 0, 0);
#pragma unroll
        for (int nt = 0; nt < 4; ++nt) {
            const int vert = n0 + nt * 16 + o16;
            if (vert < NT) {
#pragma unroll
                for (int mt = 0; mt < 2; ++mt) {
                    uint2 p;
                    p.x = (unsigned)f2bf(fmaxf(acc[mt][nt][0] + c1r[mt][0], 0.f)) |
                          ((unsigned)f2bf(fmaxf(acc[mt][nt][1] + c1r[mt][1], 0.f)) << 16);
                    p.y = (unsigned)f2bf(fmaxf(acc[mt][nt][2] + c1r[mt][2], 0.f)) |
                          ((unsigned)f2bf(fmaxf(acc[mt][nt][3] + c1r[mt][3], 0.f)) << 16);
                    *(uint2*)(y1 + (size_t)vert * 32 + mt * 16 + kg * 4) = p;
                }
            }
        }
    }
}

// ---------------- meshconv v2 (round-8 proven): 2-vertex gathers, wave-uniform metadata ----------------
__global__ __launch_bounds__(256, 4) void k_meshconv(const ushort_t* __restrict__ y1,
                                                     const ushort_t* __restrict__ cfb,
                                                     const int* __restrict__ idx_L,
                                                     const float* __restrict__ vals_L,
                                                     const int* __restrict__ i18,
                                                     const float* __restrict__ w18ew,
                                                     const float* __restrict__ w18ns,
                                                     ushort_t* __restrict__ h2,
                                                     float* __restrict__ ws) {
    __shared__ __align__(16) ushort_t feat[4][32 * FSTR];
    __shared__ float sred[64];
    const int tid = threadIdx.x;
    const int w = __builtin_amdgcn_readfirstlane(tid >> 6);
    const int lane = tid & 63;
    ushort_t* fw = &feat[w][0];
    const int gh = lane >> 5;
    const int bh = (lane >> 4) & 1;
    const int c2 = lane & 15;
    const int ybase = bh * (NV * 32);
    const int o16 = lane & 15;
    const int kg = lane >> 4;  // 0..3 (MFMA roles)

    if (tid < 64) sred[tid] = 0.f;
    __syncthreads();

    float ssum[8], sssq[8];
#pragma unroll
    for (int i = 0; i < 8; ++i) { ssum[i] = 0.f; sssq[i] = 0.f; }

    const int gw = blockIdx.x * 4 + w;
    const int NW = gridDim.x * 4;
    const int NCH = (NV + 15) >> 4;  // 10241

    for (int ch = gw; ch < NCH; ch += NW) {
        const int n0 = ch << 4;
        for (int jj = 0; jj < 8; ++jj) {
            const int gA = 2 * jj;                   // wave-uniform vertex pair
            const int nA = n0 + gA;
            const int nB = nA + 1;
            const int nnA = (nA < NV) ? nA : NV - 1;
            const int nnB = (nB < NV) ? nB : NV - 1;
            const int n = n0 + gA + gh;
            const bool ok = (n < NV);
            const int nn = gh ? nnB : nnA;
            const ushort_t* yb = y1 + ybase;
            unsigned int qs = *(const unsigned int*)(yb + (nn << 5) + (c2 << 1));
            float fx0 = bf2f((ushort_t)(qs & 0xffffu));
            float fx1 = bf2f((ushort_t)(qs >> 16));
            float lap0 = 0.f, lap1 = 0.f, ge0 = 0.f, ge1 = 0.f, gn0 = 0.f, gn1 = 0.f;
#pragma unroll
            for (int j = 0; j < 7; ++j) {
                const int viA = idx_L[nnA * 7 + j];
                const int viB = idx_L[nnB * 7 + j];
                const float wvA = vals_L[nnA * 7 + j];
                const float wvB = vals_L[nnB * 7 + j];
                const int vi = gh ? viB : viA;
                const float wv = gh ? wvB : wvA;
                unsigned int q = *(const unsigned int*)(yb + (vi << 5) + (c2 << 1));
                lap0 += wv * bf2f((ushort_t)(q & 0xffffu));
                lap1 += wv * bf2f((ushort_t)(q >> 16));
            }
#pragma unroll
            for (int j = 0; j < 18; ++j) {
                const int viA = i18[nnA * 18 + j];
                const int viB = i18[nnB * 18 + j];
                const float weA = w18ew[nnA * 18 + j];
                const float weB = w18ew[nnB * 18 + j];
                const float wnA = w18ns[nnA * 18 + j];
                const float wnB = w18ns[nnB * 18 + j];
                const int vi = gh ? viB : viA;
                const float we = gh ? weB : weA;
                const float wn = gh ? wnB : wnA;
                unsigned int q = *(const unsigned int*)(yb + (vi << 5) + (c2 << 1));
                float v0 = bf2f((ushort_t)(q & 0xffffu));
                float v1 = bf2f((ushort_t)(q >> 16));
                ge0 += we * v0; ge1 += we * v1;
                gn0 += wn * v0; gn1 += wn * v1;
            }
            unsigned int u0 = 0u, u1 = 0u, u2 = 0u, u3 = 0u;
            if (ok) {
                u0 = (unsigned int)f2bf(fx0) | ((unsigned int)f2bf(lap0) << 16);
                u1 = (unsigned int)f2bf(ge0) | ((unsigned int)f2bf(gn0) << 16);
                u2 = (unsigned int)f2bf(fx1) | ((unsigned int)f2bf(lap1) << 16);
                u3 = (unsigned int)f2bf(ge1) | ((unsigned int)f2bf(gn1) << 16);
            }
            const int inst = bh * 16 + gA + gh;
            *(uint4*)(fw + inst * FSTR + (c2 << 3)) = make_uint4(u0, u1, u2, u3);
        }
        f32x4 acc[2][2];
#pragma unroll
        for (int mt = 0; mt < 2; ++mt)
#pragma unroll
            for (int nt = 0; nt < 2; ++nt) acc[mt][nt] = (f32x4){0.f, 0.f, 0.f, 0.f};
        bf16x8 bfr[2][4];
#pragma unroll
        for (int nt = 0; nt < 2; ++nt)
#pragma unroll
            for (int kt = 0; kt < 4; ++kt)
                bfr[nt][kt] = *(const bf16x8*)(fw + (nt * 16 + o16) * FSTR + kt * 32 + kg * 8);
#pragma unroll
        for (int mt = 0; mt < 2; ++mt) {
#pragma unroll
            for (int kt = 0; kt < 4; ++kt) {
                bf16x8 af = *(const bf16x8*)(cfb + (mt * 16 + o16) * 128 + kt * 32 + kg * 8);
                acc[mt][0] = __builtin_amdgcn_mfma_f32_16x16x32_bf16(af, bfr[0][kt], acc[mt][0], 0, 0, 0);
                acc[mt][1] = __builtin_amdgcn_mfma_f32_16x16x32_bf16(af, bfr[1][kt], acc[mt][1], 0, 0, 0);
            }
        }
        const int n = n0 + o16;
        if (n < NV) {
#pragma unroll
            for (int nt = 0; nt < 2; ++nt) {
                const int rowb = ((nt * NV + n) << 5);
#pragma unroll
                for (int mt = 0; mt < 2; ++mt) {
#pragma unroll
                    for (int r = 0; r < 4; ++r) {
                        float v = acc[mt][nt][r];
                        int o = mt * 16 + kg * 4 + r;
                        h2[rowb + o] = f2bf(v);
                        ssum[mt * 4 + r] += v;
                        sssq[mt * 4 + r] += v * v;
                    }
                }
            }
        }
    }

#pragma unroll
    for (int si = 0; si < 8; ++si) {
#pragma unroll
        for (int m = 1; m < 16; m <<= 1) {
            ssum[si] += __shfl_xor(ssum[si], m, 16);
            sssq[si] += __shfl_xor(sssq[si], m, 16);
        }
    }
    if (o16 == 0) {
#pragma unroll
        for (int mt = 0; mt < 2; ++mt)
#pragma unroll
            for (int r = 0; r < 4; ++r) {
                int o = mt * 16 + kg * 4 + r;
                atomicAdd(&sred[o], ssum[mt * 4 + r]);
                atomicAdd(&sred[32 + o], sssq[mt * 4 + r]);
            }
    }
    __syncthreads();
    if (tid < 64) atomicAdd(&ws[F_S2S + tid], sred[tid]);
}

// ---------------- hr moments (fold2 fused as prologue) ----------------
__global__ __launch_bounds__(256) void k_hrmoments(const ushort_t* __restrict__ h2,
                                                   const float* __restrict__ g2,
                                                   const float* __restrict__ be2,
                                                   float* __restrict__ ws) {
    __shared__ __align__(16) ushort_t tile[4][32 * 40];
    __shared__ float red[1056];
    __shared__ float sA2[32], sC2[32];
    const int tid = threadIdx.x;
    const int w = tid >> 6, l = tid & 63;
    ushort_t* T = &tile[w][0];
    const int c8 = (l & 3) * 8;
    const int v0 = l >> 2;
    const int fr = l & 15, kg = l >> 4;

    if (tid < 32) {
        const float invN = 1.0f / (float)NT;
        float m = ws[F_S2S + tid] * invN;
        float var = ws[F_S2Q + tid] * invN - m * m;
        float a = g2[tid] * rsqrtf(var + EPSB);
        float c = be2[tid] - a * m;
        sA2[tid] = a; sC2[tid] = c;
        ws[F_A2 + tid] = a; ws[F_C2 + tid] = c;
    }
    for (int i = tid; i < 1056; i += 256) red[i] = 0.f;
    __syncthreads();

    float a2r[8], c2r[8];
#pragma unroll
    for (int j = 0; j < 8; ++j) { a2r[j] = sA2[c8 + j]; c2r[j] = sC2[c8 + j]; }

    f32x4 acc[2][2];
#pragma unroll
    for (int a = 0; a < 2; ++a)
#pragma unroll
        for (int b = 0; b < 2; ++b) acc[a][b] = (f32x4){0.f, 0.f, 0.f, 0.f};
    float ssum[8];
#pragma unroll
    for (int j = 0; j < 8; ++j) ssum[j] = 0.f;

    const int NCH = (NT + 31) >> 5;
    for (int ch = blockIdx.x * 4 + w; ch < NCH; ch += gridDim.x * 4) {
        const int s0 = ch << 5;
#pragma unroll
        for (int i = 0; i < 2; ++i) {
            const int vert = i * 16 + v0;
            const int s = s0 + vert;
            uint4 q = make_uint4(0u, 0u, 0u, 0u);
            const bool ok = (s < NT);
            if (ok) q = *(const uint4*)(h2 + (size_t)s * 32 + c8);
            const ushort_t* qs = (const ushort_t*)&q;
            ushort_t hb[8];
#pragma unroll
            for (int j = 0; j < 8; ++j) {
                float hv = ok ? fmaxf(a2r[j] * bf2f(qs[j]) + c2r[j], 0.f) : 0.f;
                ssum[j] += hv;
                hb[j] = f2bf(hv);
            }
#pragma unroll
            for (int j = 0; j < 8; ++j) T[(c8 + j) * 40 + vert] = hb[j];
        }
        bf16x8 f0 = *(const bf16x8*)(T + fr * 40 + kg * 8);
        bf16x8 f1 = *(const bf16x8*)(T + (16 + fr) * 40 + kg * 8);
        acc[0][0] = __builtin_amdgcn_mfma_f32_16x16x32_bf16(f0, f0, acc[0][0], 0, 0, 0);
        acc[0][1] = __builtin_amdgcn_mfma_f32_16x16x32_bf16(f0, f1, acc[0][1], 0, 0, 0);
        acc[1][0] = __builtin_amdgcn_mfma_f32_16x16x32_bf16(f1, f0, acc[1][0], 0, 0, 0);
        acc[1][1] = __builtin_amdgcn_mfma_f32_16x16x32_bf16(f1, f1, acc[1][1], 0, 0, 0);
    }
#pragma unroll
    for (int mt = 0; mt < 2; ++mt)
#pragma unroll
        for (int nt = 0; nt < 2; ++nt)
#pragma unroll
            for (int r = 0; r < 4; ++r)
                atomicAdd(&red[(mt * 16 + kg * 4 + r) * 32 + nt * 16 + fr], acc[mt][nt][r]);
#pragma unroll
    for (int j = 0; j < 8; ++j) {
        float s = ssum[j];
        s += __shfl_xor(s, 4); s += __shfl_xor(s, 8);
        s += __shfl_xor(s, 16); s += __shfl_xor(s, 32);
        if (v0 == 0) atomicAdd(&red[1024 + c8 + j], s);
    }
    __syncthreads();
    for (int i = tid; i < 1024; i += 256) atomicAdd(&ws[F_SS2 + i], red[i]);
    if (tid < 32) atomicAdd(&ws[F_SHR + tid], red[1024 + tid]);
}

// ---------------- fold3: BN3 params + fused final weights Wf (bf16) ----------------
__global__ __launch_bounds__(128) void k_fold3(const float* __restrict__ w3,
                                               const float* __restrict__ wsc,
                                               const float* __restrict__ g3,
                                               const float* __restrict__ be3,
                                               float* __restrict__ ws,
                                               ushort_t* __restrict__ wfb) {
    __shared__ float SSl[1024];
    __shared__ float Sl[32];
    const int tid = threadIdx.x;
    for (int i = tid; i < 1024; i += 128) SSl[i] = ws[F_SS2 + i];
    if (tid < 32) Sl[tid] = ws[F_SHR + tid];
    __syncthreads();
    const int o = tid;
    float4 wr[8];
#pragma unroll
    for (int i = 0; i < 8; ++i) wr[i] = *(const float4*)(w3 + o * 32 + i * 4);
    float dotm = 0.f, quad = 0.f;
#pragma unroll
    for (int i4 = 0; i4 < 8; ++i4) {
        float4 wi = wr[i4];
        float rd[4] = {0.f, 0.f, 0.f, 0.f};
#pragma unroll
        for (int j4 = 0; j4 < 8; ++j4) {
            float4 wj = wr[j4];
#pragma unroll
            for (int r = 0; r < 4; ++r) {
                const float* row = &SSl[(i4 * 4 + r) * 32 + j4 * 4];
                rd[r] += row[0] * wj.x + row[1] * wj.y + row[2] * wj.z + row[3] * wj.w;
            }
        }
        dotm += wi.x * Sl[i4 * 4] + wi.y * Sl[i4 * 4 + 1] + wi.z * Sl[i4 * 4 + 2] + wi.w * Sl[i4 * 4 + 3];
        quad += wi.x * rd[0] + wi.y * rd[1] + wi.z * rd[2] + wi.w * rd[3];
    }
    const float invN = 1.0f / (float)NT;
    const float mean0 = dotm * invN;
    const float var = quad * invN - mean0 * mean0;
    const float a = g3[o] * rsqrtf(var + EPSB);
    const float cbias = be3[o] - a * mean0;
    ws[F_A3 + o] = a;
    ws[F_C3 + o] = cbias;
    const float asc = ws[F_ASC + o], csc = ws[F_CSC + o];
    ws[F_CF + o] = cbias + csc;
#pragma unroll
    for (int i4 = 0; i4 < 8; ++i4) {
        wfb[o * 96 + i4 * 4 + 0] = f2bf(a * wr[i4].x);
        wfb[o * 96 + i4 * 4 + 1] = f2bf(a * wr[i4].y);
        wfb[o * 96 + i4 * 4 + 2] = f2bf(a * wr[i4].z);
        wfb[o * 96 + i4 * 4 + 3] = f2bf(a * wr[i4].w);
    }
    for (int j = 0; j < 64; ++j)
        wfb[o * 96 + 32 + j] = f2bf(asc * wsc[o * 64 + j]);
}

// ---------------- final: fused [conv3+bn3 | conv_sc+bn_sc] MFMA GEMM + relu (direct stores) ----------------
__global__ __launch_bounds__(256) void k_final(const ushort_t* __restrict__ xb,
                                               const ushort_t* __restrict__ h2,
                                               const ushort_t* __restrict__ wfb,
                                               const float* __restrict__ ws,
                                               float* __restrict__ out) {
    __shared__ __align__(16) ushort_t feat[32 * 104];
    const int tid = threadIdx.x;
    const int w = tid >> 6, l = tid & 63;
    const int fr = l & 15, kg = l >> 4;

    bf16x8 af[2][3];
#pragma unroll
    for (int mt = 0; mt < 2; ++mt)
#pragma unroll
        for (int kt = 0; kt < 3; ++kt)
            af[mt][kt] = *(const bf16x8*)(wfb + (w * 32 + mt * 16 + fr) * 96 + kt * 32 + kg * 8);
    float cfr[2][4];
#pragma unroll
    for (int mt = 0; mt < 2; ++mt)
#pragma unroll
        for (int r = 0; r < 4; ++r)
            cfr[mt][r] = ws[F_CF + w * 32 + mt * 16 + kg * 4 + r];

    const int hv = tid >> 3, hc4 = (tid & 7) * 4;
    float a2r[4], c2r[4];
#pragma unroll
    for (int j = 0; j < 4; ++j) { a2r[j] = ws[F_A2 + hc4 + j]; c2r[j] = ws[F_C2 + hc4 + j]; }
    const int xv = tid >> 3, xseg = tid & 7;

    const int NCHK = (NV + 31) >> 5;  // 5121
    for (int cid = blockIdx.x; cid < 2 * NCHK; cid += gridDim.x) {
        const int b = (cid >= NCHK) ? 1 : 0;
        const int t = cid - b * NCHK;
        const int n0 = t << 5;
        const int rem = NV - n0 < 32 ? NV - n0 : 32;
        {
            const int s = b * NV + n0 + hv;
            const bool ok = (hv < rem);
            uint2 q = make_uint2(0u, 0u);
            if (ok) q = *(const uint2*)(h2 + (size_t)s * 32 + hc4);
            const ushort_t* qs = (const ushort_t*)&q;
            unsigned int p0 = 0u, p1 = 0u;
            if (ok) {
                float h0 = fmaxf(a2r[0] * bf2f(qs[0]) + c2r[0], 0.f);
                float h1 = fmaxf(a2r[1] * bf2f(qs[1]) + c2r[1], 0.f);
                float h2v = fmaxf(a2r[2] * bf2f(qs[2]) + c2r[2], 0.f);
                float h3 = fmaxf(a2r[3] * bf2f(qs[3]) + c2r[3], 0.f);
                p0 = (unsigned int)f2bf(h0) | ((unsigned int)f2bf(h1) << 16);
                p1 = (unsigned int)f2bf(h2v) | ((unsigned int)f2bf(h3) << 16);
            }
            *(uint2*)(feat + hv * 104 + hc4) = make_uint2(p0, p1);
        }
        {
            const int s = b * NV + n0 + xv;
            uint4 q = make_uint4(0u, 0u, 0u, 0u);
            if (xv < rem) q = *(const uint4*)(xb + (size_t)s * 64 + xseg * 8);
            *(uint4*)(feat + xv * 104 + 32 + xseg * 8) = q;
        }
        __syncthreads();
        bf16x8 bf[2][3];
#pragma unroll
        for (int nt = 0; nt < 2; ++nt)
#pragma unroll
            for (int kt = 0; kt < 3; ++kt)
                bf[nt][kt] = *(const bf16x8*)(feat + (nt * 16 + fr) * 104 + kt * 32 + kg * 8);
        __syncthreads();
        f32x4 acc[2][2];
#pragma unroll
        for (int mt = 0; mt < 2; ++mt)
#pragma unroll
            for (int nt = 0; nt < 2; ++nt) acc[mt][nt] = (f32x4){0.f, 0.f, 0.f, 0.f};
#pragma unroll
        for (int mt = 0; mt < 2; ++mt)
#pragma unroll
            for (int nt = 0; nt < 2; ++nt)
#pragma unroll
                for (int kt = 0; kt < 3; ++kt)
                    acc[mt][nt] = __builtin_amdgcn_mfma_f32_16x16x32_bf16(af[mt][kt], bf[nt][kt], acc[mt][nt], 0, 0, 0);
#pragma unroll
        for (int mt = 0; mt < 2; ++mt) {
#pragma unroll
            for (int nt = 0; nt < 2; ++nt) {
                const int col = n0 + nt * 16 + fr;
                if (col < NV) {
                    float* po = out + (size_t)(b * 128 + w * 32 + mt * 16 + kg * 4) * NV + col;
#pragma unroll
                    for (int r = 0; r < 4; ++r)
                        po[(size_t)r * NV] = fmaxf(acc[mt][nt][r] + cfr[mt][r], 0.f);
                }
            }
        }
    }
}

extern "C" void kernel_launch(void* const* d_in, const int* in_sizes, int n_in,
                              void* d_out, int out_size, void* d_ws, size_t ws_size,
                              hipStream_t stream) {
    (void)in_sizes; (void)n_in; (void)out_size; (void)ws_size;
    const float* x        = (const float*)d_in[0];
    const float* w1       = (const float*)d_in[1];
    const float* g1       = (const float*)d_in[3];
    const float* be1      = (const float*)d_in[4];
    const float* coeffs   = (const float*)d_in[5];
    const float* g2       = (const float*)d_in[7];
    const float* be2      = (const float*)d_in[8];
    const float* w3       = (const float*)d_in[9];
    const float* g3       = (const float*)d_in[11];
    const float* be3      = (const float*)d_in[12];
    const float* wsc      = (const float*)d_in[13];
    const float* gsc      = (const float*)d_in[15];
    const float* besc     = (const float*)d_in[16];
    const int*   idx_G    = (const int*)d_in[17];
    const float* vals_G   = (const float*)d_in[18];
    const float* EW       = (const float*)d_in[19];
    const float* NS       = (const float*)d_in[20];
    const int*   idx_L    = (const int*)d_in[21];
    const float* vals_L   = (const float*)d_in[22];
    const int*   idx_F2V  = (const int*)d_in[23];
    const float* vals_F2V = (const float*)d_in[24];
    float* ws  = (float*)d_ws;
    float* out = (float*)d_out;

    ushort_t* w1b = (ushort_t*)(ws + F_W1B);
    ushort_t* cfb = (ushort_t*)(ws + F_CFB);
    ushort_t* y1  = (ushort_t*)(ws + F_Y1);
    ushort_t* h2  = (ushort_t*)(ws + F_H2);
    ushort_t* xb  = (ushort_t*)(ws + F_XB);
    ushort_t* wfb = (ushort_t*)(ws + F_Y1);  // aliases y1 (dead after meshconv)
    float*    frec = ws + F_XB;              // aliases xb (consumed before xb written)

    hipMemsetAsync(ws, 0, STATN * sizeof(float), stream);
    hipLaunchKernelGGL(k_face, dim3((NF + 255) / 256), dim3(256), 0, stream,
                       idx_G, vals_G, EW, NS, frec);
    hipLaunchKernelGGL(k_prep, dim3((NV + 255) / 256), dim3(256), 0, stream,
                       idx_F2V, vals_F2V, frec, coeffs,
                       (int*)(ws + F_I18), ws + F_WEW, ws + F_WNS, cfb);
    hipLaunchKernelGGL(k_xcvt, dim3(1280), dim3(256), 0, stream, x, ws, xb);
    hipLaunchKernelGGL(k_fold1, dim3(5), dim3(256), 0, stream, w1, g1, be1, wsc, gsc, besc, ws, w1b);
    hipLaunchKernelGGL(k_conv1, dim3(1280), dim3(256), 0, stream, xb, w1b, ws, y1);
    hipLaunchKernelGGL(k_meshconv, dim3(1024), dim3(256), 0, stream,
                       y1, cfb, idx_L, vals_L,
                       (const int*)(ws + F_I18), ws + F_WEW, ws + F_WNS,
                       h2, ws);
    hipLaunchKernelGGL(k_hrmoments, dim3(1024), dim3(256), 0, stream, h2, g2, be2, ws);
    hipLaunchKernelGGL(k_fold3, dim3(1), dim3(128), 0, stream, w3, wsc, g3, be3, ws, wfb);
    hipLaunchKernelGGL(k_final, dim3(2048), dim3(256), 0, stream, xb, h2, wfb, ws, out);
}